// Round 10
// baseline (256.024 us; speedup 1.0000x reference)
//
#include <hip/hip_runtime.h>
#include <hip/hip_bf16.h>
#include <math.h>

#define HIDDEN 1024
#define HEADS 16
#define HEAD_DIM 64
#define POS_DIM 128
#define BATCH 2
#define SEQ 2048
#define TOKENS (BATCH * SEQ)

typedef _Float16 f16;
typedef __attribute__((ext_vector_type(8))) _Float16 f16x8;
typedef __attribute__((ext_vector_type(4))) _Float16 f16x4;
typedef __attribute__((ext_vector_type(4))) float f32x4;

// async global->LDS, 16B per lane; LDS dest = wave-uniform base + lane*16
__device__ __forceinline__ void glds16(const f16* g, f16* l) {
    __builtin_amdgcn_global_load_lds((const __attribute__((address_space(1))) unsigned int*)g,
                                     (__attribute__((address_space(3))) unsigned int*)l, 16, 0, 0);
}

// ---------------------------------------------------------------------------
// cast x (fp32 -> f16), 8 elems/thread
// ---------------------------------------------------------------------------
__global__ __launch_bounds__(256) void cast_x_kernel(const float* __restrict__ x,
                                                     f16* __restrict__ o) {
    const int i = (blockIdx.x * 256 + threadIdx.x) * 8;
    const float4 u = *(const float4*)(x + i);
    const float4 v = *(const float4*)(x + i + 4);
    f16x8 r = {(f16)u.x, (f16)u.y, (f16)u.z, (f16)u.w,
               (f16)v.x, (f16)v.y, (f16)v.z, (f16)v.w};
    *(f16x8*)(o + i) = r;
}

// ---------------------------------------------------------------------------
// 4 weights [1024][1024] fp32 -> Wt f16 transposed, z-indexed (1 launch)
// ---------------------------------------------------------------------------
__global__ __launch_bounds__(256) void cast_wt4_kernel(const float* __restrict__ W0,
                                                       const float* __restrict__ W1,
                                                       const float* __restrict__ W2,
                                                       const float* __restrict__ W3,
                                                       f16* __restrict__ Wt) {
    __shared__ float ts[32][33];
    const int t = threadIdx.x;
    const int z = blockIdx.z;
    const float* W = (z == 0) ? W0 : (z == 1) ? W1 : (z == 2) ? W2 : W3;
    f16* dst = Wt + (size_t)z * HIDDEN * HIDDEN;
    const int k0 = blockIdx.y * 32, n0 = blockIdx.x * 32;
    {
        const int r = t >> 3, c4 = (t & 7) * 4;
        const float4 u = *(const float4*)(W + (size_t)(k0 + r) * HIDDEN + n0 + c4);
        ts[r][c4 + 0] = u.x; ts[r][c4 + 1] = u.y; ts[r][c4 + 2] = u.z; ts[r][c4 + 3] = u.w;
    }
    __syncthreads();
    {
        const int r = t >> 3, c4 = (t & 7) * 4;
        f16* o = dst + (size_t)(n0 + r) * HIDDEN + k0 + c4;
        o[0] = (f16)ts[c4 + 0][r]; o[1] = (f16)ts[c4 + 1][r];
        o[2] = (f16)ts[c4 + 2][r]; o[3] = (f16)ts[c4 + 3][r];
    }
}

// ---------------------------------------------------------------------------
// W1 [1024][128] fp32 -> w1t_hi/lo [128][1024] f16 split (transpose)
// ---------------------------------------------------------------------------
__global__ __launch_bounds__(256) void cast_w1t_kernel(const float* __restrict__ W1,
                                                       f16* __restrict__ Wh,
                                                       f16* __restrict__ Wl) {
    __shared__ float ts[32][33];
    const int t = threadIdx.x;
    const int k0 = blockIdx.y * 32, p0 = blockIdx.x * 32;
    {
        const int r = t >> 3, c4 = (t & 7) * 4;
        const float4 u = *(const float4*)(W1 + (size_t)(k0 + r) * POS_DIM + p0 + c4);
        ts[r][c4 + 0] = u.x; ts[r][c4 + 1] = u.y; ts[r][c4 + 2] = u.z; ts[r][c4 + 3] = u.w;
    }
    __syncthreads();
    {
        const int r = t >> 3, c4 = (t & 7) * 4;
        f16* oh = Wh + (size_t)(p0 + r) * HIDDEN + k0 + c4;
        f16* ol = Wl + (size_t)(p0 + r) * HIDDEN + k0 + c4;
#pragma unroll
        for (int u = 0; u < 4; ++u) {
            const float v = ts[c4 + u][r];
            const f16 hi = (f16)v;
            oh[u] = hi;
            ol[u] = (f16)(v - (float)hi);
        }
    }
}

// ---------------------------------------------------------------------------
// m97-style f16 MFMA GEMM: C[4096][N] = A[4096][1024] @ Bt[N][1024]^T.
// r9-proven operand SWAP epilogue: mfma(bf, af) -> D register dim runs along
// N -> vectorized f16x4/f32x4 stores, bitwise-identical C.
// ---------------------------------------------------------------------------
__global__ __launch_bounds__(256, 3) void gemm_gll(const f16* __restrict__ A,
                                                   const f16* __restrict__ Bt,
                                                   f16* __restrict__ Cb,
                                                   float* __restrict__ Cf,
                                                   int N, int f16out) {
    __shared__ __align__(16) f16 As[128 * 64];  // [row][slot*8], slot = seg ^ (row&7)
    __shared__ __align__(16) f16 Bs[128 * 64];
    const int tid = threadIdx.x;
    const int w = tid >> 6, lane = tid & 63;
    const int g = lane >> 4, c = lane & 15;
    const int m0 = blockIdx.y * 128, n0 = blockIdx.x * 128;
    const int wm = (w & 1) * 64, wn = (w >> 1) * 64;

    const int lrow = lane >> 3;            // 0..7
    const int lseg = (lane & 7) ^ lrow;    // XOR swizzle on global k-segment
    const f16* gA = A + (size_t)(m0 + w * 32 + lrow) * 1024 + lseg * 8;
    const f16* gB = Bt + (size_t)(n0 + w * 32 + lrow) * 1024 + lseg * 8;
    f16* lA = &As[(w * 32) * 64];
    f16* lB = &Bs[(w * 32) * 64];

    f32x4 acc[4][4];
    const f32x4 z = {0.f, 0.f, 0.f, 0.f};
#pragma unroll
    for (int i = 0; i < 4; ++i)
#pragma unroll
        for (int j = 0; j < 4; ++j) acc[i][j] = z;

    const int rsw = c & 7;
    for (int k0 = 0; k0 < 1024; k0 += 64) {
        __syncthreads();
#pragma unroll
        for (int p = 0; p < 4; ++p) {
            glds16(gA + (size_t)p * 8 * 1024 + k0, lA + p * 8 * 64);
            glds16(gB + (size_t)p * 8 * 1024 + k0, lB + p * 8 * 64);
        }
        __syncthreads();
#pragma unroll
        for (int s = 0; s < 2; ++s) {
            f16x8 af[4], bf[4];
#pragma unroll
            for (int i = 0; i < 4; ++i)
                af[i] = *(const f16x8*)&As[(wm + i * 16 + c) * 64 + (((s * 4 + g) ^ rsw) * 8)];
#pragma unroll
            for (int j = 0; j < 4; ++j)
                bf[j] = *(const f16x8*)&Bs[(wn + j * 16 + c) * 64 + (((s * 4 + g) ^ rsw) * 8)];
#pragma unroll
            for (int i = 0; i < 4; ++i)
#pragma unroll
                for (int j = 0; j < 4; ++j)
                    acc[i][j] = __builtin_amdgcn_mfma_f32_16x16x32_f16(bf[j], af[i], acc[i][j], 0, 0, 0);
        }
    }
    // swapped D-layout: acc[i][j][r] = C[m0+wm+i*16+c][n0+wn+j*16+4g+r]
#pragma unroll
    for (int i = 0; i < 4; ++i)
#pragma unroll
        for (int j = 0; j < 4; ++j) {
            const size_t off = (size_t)(m0 + wm + i * 16 + c) * N + n0 + wn + j * 16 + 4 * g;
            if (f16out) {
                f16x4 v = {(f16)acc[i][j][0], (f16)acc[i][j][1],
                           (f16)acc[i][j][2], (f16)acc[i][j][3]};
                *(f16x4*)(Cb + off) = v;
            } else {
                *(f32x4*)(Cf + off) = acc[i][j];
            }
        }
}

// ---------------------------------------------------------------------------
// RePo MLP via split-f16 MFMA
// ---------------------------------------------------------------------------
__device__ __forceinline__ float gelu_tanh(float x) {
    const float kA = 0.7978845608028654f;
    return 0.5f * x * (1.0f + tanhf(kA * (x + 0.044715f * x * x * x)));
}

__global__ __launch_bounds__(256, 2) void repo_mfma(const float* __restrict__ x,
                                                    const f16* __restrict__ w1h,
                                                    const f16* __restrict__ w1l,
                                                    const float* __restrict__ b1,
                                                    const float* __restrict__ W2,
                                                    const float* __restrict__ b2,
                                                    float* __restrict__ raw) {
    __shared__ __align__(16) f16 Ash[64 * 32], Asl[64 * 32];
    __shared__ __align__(16) f16 Bsh[128 * 32], Bsl[128 * 32];
    __shared__ float red[4][64];
    const int tid = threadIdx.x;
    const int w = tid >> 6, lane = tid & 63;
    const int g = lane >> 4, c = lane & 15;
    const int m0 = blockIdx.x * 64;

    const int arow = tid >> 2, aseg = tid & 3;
    const int aslot = (aseg ^ ((arow ^ (arow >> 2)) & 3)) << 3;
    const float* gA = x + (size_t)(m0 + arow) * 1024 + aseg * 8;
    const f16* gBh0 = w1h + (size_t)arow * 1024 + aseg * 8;
    const f16* gBh1 = w1h + (size_t)(arow + 64) * 1024 + aseg * 8;
    const f16* gBl0 = w1l + (size_t)arow * 1024 + aseg * 8;
    const f16* gBl1 = w1l + (size_t)(arow + 64) * 1024 + aseg * 8;
    f16* sAh = &Ash[arow * 32 + aslot];
    f16* sAl = &Asl[arow * 32 + aslot];
    f16* sBh0 = &Bsh[arow * 32 + aslot];
    f16* sBh1 = &Bsh[(arow + 64) * 32 + aslot];
    f16* sBl0 = &Bsl[arow * 32 + aslot];
    f16* sBl1 = &Bsl[(arow + 64) * 32 + aslot];

    const int foff = ((g ^ ((c ^ (c >> 2)) & 3)) << 3);

    f32x4 acc[4][2];
    const f32x4 z = {0.f, 0.f, 0.f, 0.f};
#pragma unroll
    for (int i = 0; i < 4; ++i) { acc[i][0] = z; acc[i][1] = z; }

    float4 pa0 = *(const float4*)gA;
    float4 pa1 = *(const float4*)(gA + 4);
    f16x8 pbh0 = *(const f16x8*)gBh0, pbh1 = *(const f16x8*)gBh1;
    f16x8 pbl0 = *(const f16x8*)gBl0, pbl1 = *(const f16x8*)gBl1;

    for (int k0 = 0; k0 < 1024; k0 += 32) {
        __syncthreads();
        {
            const float av[8] = {pa0.x, pa0.y, pa0.z, pa0.w, pa1.x, pa1.y, pa1.z, pa1.w};
            f16x8 ah, al;
#pragma unroll
            for (int u = 0; u < 8; ++u) {
                const f16 hi = (f16)av[u];
                ah[u] = hi;
                al[u] = (f16)(av[u] - (float)hi);
            }
            *(f16x8*)sAh = ah; *(f16x8*)sAl = al;
            *(f16x8*)sBh0 = pbh0; *(f16x8*)sBh1 = pbh1;
            *(f16x8*)sBl0 = pbl0; *(f16x8*)sBl1 = pbl1;
        }
        __syncthreads();
        if (k0 + 32 < 1024) {
            pa0 = *(const float4*)(gA + k0 + 32);
            pa1 = *(const float4*)(gA + k0 + 36);
            pbh0 = *(const f16x8*)(gBh0 + k0 + 32);
            pbh1 = *(const f16x8*)(gBh1 + k0 + 32);
            pbl0 = *(const f16x8*)(gBl0 + k0 + 32);
            pbl1 = *(const f16x8*)(gBl1 + k0 + 32);
        }
        f16x8 ah[4], al[4], bh[2], bl[2];
#pragma unroll
        for (int i = 0; i < 4; ++i) {
            ah[i] = *(const f16x8*)&Ash[(i * 16 + c) * 32 + foff];
            al[i] = *(const f16x8*)&Asl[(i * 16 + c) * 32 + foff];
        }
#pragma unroll
        for (int j = 0; j < 2; ++j) {
            bh[j] = *(const f16x8*)&Bsh[(w * 32 + j * 16 + c) * 32 + foff];
            bl[j] = *(const f16x8*)&Bsl[(w * 32 + j * 16 + c) * 32 + foff];
        }
#pragma unroll
        for (int i = 0; i < 4; ++i)
#pragma unroll
            for (int j = 0; j < 2; ++j) {
                acc[i][j] = __builtin_amdgcn_mfma_f32_16x16x32_f16(ah[i], bh[j], acc[i][j], 0, 0, 0);
                acc[i][j] = __builtin_amdgcn_mfma_f32_16x16x32_f16(ah[i], bl[j], acc[i][j], 0, 0, 0);
                acc[i][j] = __builtin_amdgcn_mfma_f32_16x16x32_f16(al[i], bh[j], acc[i][j], 0, 0, 0);
            }
    }
    float b1v[2], w2v[2];
#pragma unroll
    for (int j = 0; j < 2; ++j) {
        const int col = w * 32 + j * 16 + c;
        b1v[j] = b1[col];
        w2v[j] = W2[col];
    }
    float part[4][4];
#pragma unroll
    for (int i = 0; i < 4; ++i)
#pragma unroll
        for (int r = 0; r < 4; ++r) {
            float s = 0.f;
#pragma unroll
            for (int j = 0; j < 2; ++j)
                s += gelu_tanh(acc[i][j][r] + b1v[j]) * w2v[j];
            s += __shfl_xor(s, 1, 64);
            s += __shfl_xor(s, 2, 64);
            s += __shfl_xor(s, 4, 64);
            s += __shfl_xor(s, 8, 64);
            part[i][r] = s;
        }
    if (c == 0)
#pragma unroll
        for (int i = 0; i < 4; ++i)
#pragma unroll
            for (int r = 0; r < 4; ++r)
                red[w][i * 16 + 4 * g + r] = part[i][r];
    __syncthreads();
    if (tid < 64)
        raw[m0 + tid] = red[0][tid] + red[1][tid] + red[2][tid] + red[3][tid] + b2[0];
}

__device__ __forceinline__ double softplus_d(double x) {
    return (x > 0.0) ? x + log1p(exp(-x)) : log1p(exp(x));
}

__global__ __launch_bounds__(256) void repo_cumsum_kernel(const float* __restrict__ raw,
                                                          float* __restrict__ pos) {
    __shared__ double bufA[256];
    __shared__ double bufB[256];
    const int b = blockIdx.x;
    const int t = threadIdx.x;
    const float* r = raw + (size_t)b * SEQ;

    double loc[8];
    double sum = 0.0;
#pragma unroll
    for (int i = 0; i < 8; ++i) {
        sum += softplus_d((double)r[t * 8 + i]);
        loc[i] = sum;
    }
    bufA[t] = sum;
    __syncthreads();

    double* src = bufA;
    double* dst = bufB;
    for (int off = 1; off < 256; off <<= 1) {
        double v = src[t];
        if (t >= off) v += src[t - off];
        dst[t] = v;
        __syncthreads();
        double* tmp = src; src = dst; dst = tmp;
    }
    const double excl = src[t] - sum;
#pragma unroll
    for (int i = 0; i < 8; ++i)
        pos[(size_t)b * SEQ + t * 8 + i] = (float)(excl + loc[i]);
}

// ---------------------------------------------------------------------------
// cos/sin table [tok][32]
// ---------------------------------------------------------------------------
__global__ __launch_bounds__(256) void sctab_kernel(const float* __restrict__ pos,
                                                    float* __restrict__ costab,
                                                    float* __restrict__ sintab) {
    const int idx = blockIdx.x * 256 + threadIdx.x;
    const int tok = idx >> 5, i = idx & 31;
    const double ang = (double)pos[tok] * exp(-(double)i * 0.28782313662425574);
    double sa, ca;
    sincos(ang, &sa, &ca);
    costab[idx] = (float)ca;
    sintab[idx] = (float)sa;
}

// ---------------------------------------------------------------------------
// Pack K (rope fused) + V into fragment-major layouts; rope Q in-place.
// Proven r7/r2 layouts: K frag f16x8 at frag*512+lane*8; V frag f16x4 at
// frag*256+lane*4.
// ---------------------------------------------------------------------------
__global__ __launch_bounds__(256) void packkv_kernel(f16* __restrict__ qkv,
                                                     const float* __restrict__ costab,
                                                     const float* __restrict__ sintab,
                                                     f16* __restrict__ kfo,
                                                     f16* __restrict__ vfo) {
    __shared__ __align__(16) f16 kds[64][72];
    __shared__ __align__(16) f16 vds[64][72];
    const int t = threadIdx.x;
    const int s0 = blockIdx.x * 64;
    const int h = blockIdx.y, b = blockIdx.z;
    const int key = t >> 2, part = t & 3;
    const int tok = b * SEQ + s0 + key;
    {
        float cs[8], sn[8];
        *(float4*)cs       = *(const float4*)(costab + tok * 32 + part * 8);
        *(float4*)(cs + 4) = *(const float4*)(costab + tok * 32 + part * 8 + 4);
        *(float4*)sn       = *(const float4*)(sintab + tok * 32 + part * 8);
        *(float4*)(sn + 4) = *(const float4*)(sintab + tok * 32 + part * 8 + 4);
        f16* qrow = qkv + (size_t)tok * 3072 + h * HEAD_DIM;
        {
            f16x8 lo = *(const f16x8*)(qrow + part * 8);
            f16x8 hi = *(const f16x8*)(qrow + part * 8 + 32);
#pragma unroll
            for (int u = 0; u < 8; ++u) {
                const float l = (float)lo[u], hh = (float)hi[u];
                lo[u] = (f16)(l * cs[u] - hh * sn[u]);
                hi[u] = (f16)(l * sn[u] + hh * cs[u]);
            }
            *(f16x8*)(qrow + part * 8) = lo;
            *(f16x8*)(qrow + part * 8 + 32) = hi;
        }
        const f16* krow = qrow + 1024;
        {
            f16x8 lo = *(const f16x8*)(krow + part * 8);
            f16x8 hi = *(const f16x8*)(krow + part * 8 + 32);
#pragma unroll
            for (int u = 0; u < 8; ++u) {
                const float l = (float)lo[u], hh = (float)hi[u];
                kds[key][part * 8 + u]      = (f16)(l * cs[u] - hh * sn[u]);
                kds[key][32 + part * 8 + u] = (f16)(l * sn[u] + hh * cs[u]);
            }
        }
        const f16* vrow = qrow + 2048;
        f16x8 v0 = *(const f16x8*)(vrow + part * 16);
        f16x8 v1 = *(const f16x8*)(vrow + part * 16 + 8);
#pragma unroll
        for (int u = 0; u < 8; ++u) {
            vds[part * 16 + u][key] = v0[u];
            vds[part * 16 + 8 + u][key] = v1[u];
        }
    }
    __syncthreads();
    const size_t cb = ((size_t)((b * HEADS + h) * 32) + blockIdx.x) * 4096;
#pragma unroll
    for (int p = 0; p < 2; ++p) {
        const int idx = p * 256 + t;
        const int frag = idx >> 6, lane = idx & 63;
        const int jn = frag >> 1, half = frag & 1, g = lane >> 4, c = lane & 15;
        *(f16x8*)(kfo + cb + frag * 512 + lane * 8) =
            *(const f16x8*)(&kds[jn * 16 + c][half * 32 + g * 8]);
    }
#pragma unroll
    for (int p = 0; p < 4; ++p) {
        const int idx = p * 256 + t;
        const int frag = idx >> 6, lane = idx & 63;
        const int jd = frag >> 2, jn = frag & 3, g = lane >> 4, c = lane & 15;
        *(f16x4*)(vfo + cb + frag * 256 + lane * 4) =
            *(const f16x4*)(&vds[jd * 16 + c][jn * 16 + 4 * g]);
    }
}

// ---------------------------------------------------------------------------
// MFMA flash attention, no split-K (r7/r9 structure). NEW this round:
// T14 reg-staging replaces glds16. r9 counters: MFMA 38.6% + VALU 41.1% +
// DEAD 20% (~11us) -- the dead time is the per-chunk glds16 drain: direct-
// to-LDS loads MUST be vmcnt(0)-drained at the barrier (no deferable use
// point). Reg-staging moves the wait: chunk cc+1 is global_load'ed into
// VGPRs right AFTER barrier #2 (in flight across the whole ~1.3us compute
// phase >> 900cy HBM latency), and ds_write'd at the next iteration top
// where the vmcnt wait is ~free. Same two barriers, same LDS layout, same
// fragment math/epilogue as r9 (passed, absmax 9.77e-4). Cost: +16 VGPR
// (4x f16x8) + 4 ds_write_b128/thread/chunk (stride-1, conflict-free).
// ---------------------------------------------------------------------------
__global__ __launch_bounds__(256, 2) void attn_f16(const f16* __restrict__ qkv,
                                                   const f16* __restrict__ kfr,
                                                   const f16* __restrict__ vfr,
                                                   f16* __restrict__ aof0) {
    __shared__ __align__(16) f16 kls[4096];     // one K chunk (8 KB)
    __shared__ __align__(16) f16 vls[4096];     // one V chunk (8 KB)
    __shared__ __align__(16) f16 ot[4][32][72]; // epilogue transpose (18 KB)
    const int tid = threadIdx.x;
    const int w = tid >> 6, lane = tid & 63;
    const int g = lane >> 4, c = lane & 15;

    // XCD-aware decode: wid -> (xcd, slot) -> (combo=(h,b), xblk)
    const int wid = blockIdx.x;                 // 0..511
    const int xcd = wid & 7, slot = wid >> 3;   // slot 0..63
    const int combo = xcd * 4 + (slot >> 4);    // 0..31: 4 (h,b) combos/XCD
    const int xblk = slot & 15;                 // 0..15
    const int h = combo & 15;
    const int b = combo >> 4;

    const int bh = b * HEADS + h;
    const int row0 = xblk * 128 + w * 32;

    const f16* qb = qkv + (size_t)(b * SEQ + row0) * 3072 + h * HEAD_DIM + g * 8;
    // per-thread staging addresses (wave w owns bytes [w*2KB, w*2KB+2KB))
    const f16* kfb = kfr + (size_t)bh * 32 * 4096 + w * 1024 + lane * 8;
    const f16* vfb = vfr + (size_t)bh * 32 * 4096 + w * 1024 + lane * 8;
    f16* kd = kls + w * 1024 + lane * 8;
    f16* vd = vls + w * 1024 + lane * 8;

    f16x8 qf[2][2];
#pragma unroll
    for (int i = 0; i < 2; ++i) {
        qf[i][0] = *(const f16x8*)(qb + (size_t)(i * 16 + c) * 3072);
        qf[i][1] = *(const f16x8*)(qb + (size_t)(i * 16 + c) * 3072 + 32);
    }
    const f32x4 z = {0.f, 0.f, 0.f, 0.f};
    f32x4 acc[4][2];
#pragma unroll
    for (int jd = 0; jd < 4; ++jd) { acc[jd][0] = z; acc[jd][1] = z; }
    float dloc[2] = {0.f, 0.f};   // denominator partials (VALU pipe)

    const float SC = 0.125f * 1.4426950408889634f;

    // prologue: chunk 0 -> regs
    f16x8 kr0 = *(const f16x8*)(kfb);
    f16x8 kr1 = *(const f16x8*)(kfb + 512);
    f16x8 vr0 = *(const f16x8*)(vfb);
    f16x8 vr1 = *(const f16x8*)(vfb + 512);

    for (int cc = 0; cc < 32; ++cc) {
        __syncthreads();   // prior chunk's ds_reads done; staging regs landed
        *(f16x8*)kd         = kr0;
        *(f16x8*)(kd + 512) = kr1;
        *(f16x8*)vd         = vr0;
        *(f16x8*)(vd + 512) = vr1;
        __syncthreads();   // ds_writes visible block-wide
        if (cc + 1 < 32) {
            // issue next chunk's loads AFTER the barrier: they stay in flight
            // across the whole compute phase (no exposed latency)
            const f16* kg = kfb + (size_t)(cc + 1) * 4096;
            const f16* vg = vfb + (size_t)(cc + 1) * 4096;
            kr0 = *(const f16x8*)(kg);
            kr1 = *(const f16x8*)(kg + 512);
            vr0 = *(const f16x8*)(vg);
            vr1 = *(const f16x8*)(vg + 512);
        }

        f16x8 kf[8];
        f16x4 vf[16];
#pragma unroll
        for (int f = 0; f < 8; ++f) kf[f] = *(const f16x8*)(kls + lane * 8 + f * 512);
#pragma unroll
        for (int f = 0; f < 16; ++f) vf[f] = *(const f16x4*)(vls + lane * 4 + f * 256);

#pragma unroll
        for (int i = 0; i < 2; ++i) {
            f32x4 s[4];
#pragma unroll
            for (int jn = 0; jn < 4; ++jn) {
                s[jn] = __builtin_amdgcn_mfma_f32_16x16x32_f16(kf[jn * 2], qf[i][0], z, 0, 0, 0);
                s[jn] = __builtin_amdgcn_mfma_f32_16x16x32_f16(kf[jn * 2 + 1], qf[i][1], s[jn], 0, 0, 0);
            }
#pragma unroll
            for (int jn = 0; jn < 4; ++jn) {
                const float e0 = __builtin_amdgcn_exp2f(fmaf(s[jn][0], SC, -8.0f));
                const float e1 = __builtin_amdgcn_exp2f(fmaf(s[jn][1], SC, -8.0f));
                const float e2 = __builtin_amdgcn_exp2f(fmaf(s[jn][2], SC, -8.0f));
                const float e3 = __builtin_amdgcn_exp2f(fmaf(s[jn][3], SC, -8.0f));
                dloc[i] += (e0 + e1) + (e2 + e3);
                f16x4 pf = {(f16)e0, (f16)e1, (f16)e2, (f16)e3};
#pragma unroll
                for (int jd = 0; jd < 4; ++jd)
                    acc[jd][i] = __builtin_amdgcn_mfma_f32_16x16x16f16(vf[jd * 4 + jn], pf, acc[jd][i], 0, 0, 0);
            }
        }
    }

    // denominators: reduce across the 4 g-groups (lanes c, 16+c, 32+c, 48+c);
    // after the two xors every lane holds the full sum for its query (i, c).
    float inv[2];
#pragma unroll
    for (int i = 0; i < 2; ++i) {
        dloc[i] += __shfl_xor(dloc[i], 16, 64);
        dloc[i] += __shfl_xor(dloc[i], 32, 64);
        inv[i] = 1.0f / dloc[i];   // 2^-8 bias cancels between num and denom
    }

    // numerator: normalize in f32, O^T regs -> wave-private LDS transpose ->
    // coalesced f16 store (single output, no combine pass)
    __syncthreads();   // all ds_reads of the last chunk done before ot reuse
#pragma unroll
    for (int i = 0; i < 2; ++i)
#pragma unroll
        for (int jd = 0; jd < 4; ++jd)
#pragma unroll
            for (int r = 0; r < 4; ++r)
                ot[w][i * 16 + c][jd * 16 + 4 * g + r] = (f16)(acc[jd][i][r] * inv[i]);
    const int tr = lane >> 1, hf = lane & 1;
    f16* aob = aof0 + (size_t)(b * SEQ + row0 + tr) * HIDDEN + h * HEAD_DIM + hf * 32;
#pragma unroll
    for (int q = 0; q < 4; ++q)
        *(f16x8*)(aob + q * 8) = *(const f16x8*)(&ot[w][tr][hf * 32 + q * 8]);
}

// ---------------------------------------------------------------------------
// launch
// ---------------------------------------------------------------------------
extern "C" void kernel_launch(void* const* d_in, const int* in_sizes, int n_in,
                              void* d_out, int out_size, void* d_ws, size_t ws_size,
                              hipStream_t stream) {
    const float* x   = (const float*)d_in[0];
    const float* W_q = (const float*)d_in[1];
    const float* W_k = (const float*)d_in[2];
    const float* W_v = (const float*)d_in[3];
    const float* W_o = (const float*)d_in[4];
    const float* rW1 = (const float*)d_in[5];
    const float* rb1 = (const float*)d_in[6];
    const float* rW2 = (const float*)d_in[7];
    const float* rb2 = (const float*)d_in[8];
    float* out = (float*)d_out;

    const size_t MAT = (size_t)TOKENS * HIDDEN;   // 4M
    const size_t WSZ = (size_t)HIDDEN * HIDDEN;   // 1M
    f16* x16  = (f16*)d_ws;
    f16* wqkv = x16 + MAT;            // [3072][1024]; wot contiguous after
    f16* wot  = wqkv + 3 * WSZ;
    f16* qkv  = wot + WSZ;            // [4096][3072]
    f16* kfr  = qkv + 3 * MAT;
    f16* vfr  = kfr + MAT;
    f16* aof0 = vfr + MAT;
    f16* aof1 = aof0 + MAT;           // unused (no split-K)
    f16* w1h  = aof1 + MAT;           // [128][1024]
    f16* w1l  = w1h + POS_DIM * HIDDEN;
    float* raw    = (float*)(w1l + POS_DIM * HIDDEN);
    float* pos    = raw + TOKENS;
    float* costab = pos + TOKENS;
    float* sintab = costab + TOKENS * 32;

    cast_x_kernel<<<MAT / 2048, 256, 0, stream>>>(x, x16);
    cast_wt4_kernel<<<dim3(32, 32, 4), 256, 0, stream>>>(W_q, W_k, W_v, W_o, wqkv);
    cast_w1t_kernel<<<dim3(4, 32), 256, 0, stream>>>(rW1, w1h, w1l);

    gemm_gll<<<dim3(24, 32), 256, 0, stream>>>(x16, wqkv, qkv, nullptr, 3072, 1);

    repo_mfma<<<64, 256, 0, stream>>>(x, w1h, w1l, rb1, rW2, rb2, raw);
    repo_cumsum_kernel<<<BATCH, 256, 0, stream>>>(raw, pos);
    sctab_kernel<<<TOKENS * 32 / 256, 256, 0, stream>>>(pos, costab, sintab);

    packkv_kernel<<<dim3(SEQ / 64, HEADS, BATCH), 256, 0, stream>>>(qkv, costab, sintab, kfr, vfr);

    attn_f16<<<dim3(512), 256, 0, stream>>>(qkv, kfr, vfr, aof0);

    gemm_gll<<<dim3(8, 32), 256, 0, stream>>>(aof0, wot, nullptr, out, 1024, 0);
}

// Round 11
// 239.776 us; speedup vs baseline: 1.0678x; 1.0678x over previous
//
#include <hip/hip_runtime.h>
#include <hip/hip_bf16.h>
#include <math.h>

#define HIDDEN 1024
#define HEADS 16
#define HEAD_DIM 64
#define POS_DIM 128
#define BATCH 2
#define SEQ 2048
#define TOKENS (BATCH * SEQ)

typedef _Float16 f16;
typedef __attribute__((ext_vector_type(8))) _Float16 f16x8;
typedef __attribute__((ext_vector_type(4))) _Float16 f16x4;
typedef __attribute__((ext_vector_type(4))) float f32x4;

// async global->LDS, 16B per lane; LDS dest = wave-uniform base + lane*16
__device__ __forceinline__ void glds16(const f16* g, f16* l) {
    __builtin_amdgcn_global_load_lds((const __attribute__((address_space(1))) unsigned int*)g,
                                     (__attribute__((address_space(3))) unsigned int*)l, 16, 0, 0);
}

// ---------------------------------------------------------------------------
// MERGED preprocessing (1 launch, was 3): block-uniform dispatch on bid.
//   [0, 2048)        : cast x fp32->f16, 8 elems/thread
//   [2048, 6144)     : 4 weights [1024][1024] -> Wt f16 transposed
//   [6144, 6272)     : W1 [1024][128] -> w1t hi/lo split transposed
// ---------------------------------------------------------------------------
__global__ __launch_bounds__(256) void cast_all_kernel(const float* __restrict__ x,
                                                       const float* __restrict__ W0,
                                                       const float* __restrict__ W1,
                                                       const float* __restrict__ W2,
                                                       const float* __restrict__ W3,
                                                       const float* __restrict__ rW1,
                                                       f16* __restrict__ x16,
                                                       f16* __restrict__ Wt,
                                                       f16* __restrict__ Wh,
                                                       f16* __restrict__ Wl) {
    __shared__ float ts[32][33];
    const int bid = blockIdx.x;
    const int t = threadIdx.x;
    if (bid < 2048) {
        const int i = (bid * 256 + t) * 8;
        const float4 u = *(const float4*)(x + i);
        const float4 v = *(const float4*)(x + i + 4);
        f16x8 r = {(f16)u.x, (f16)u.y, (f16)u.z, (f16)u.w,
                   (f16)v.x, (f16)v.y, (f16)v.z, (f16)v.w};
        *(f16x8*)(x16 + i) = r;
        return;
    }
    if (bid < 6144) {
        const int local = bid - 2048;
        const int z = local >> 10;
        const int by = (local & 1023) >> 5, bx = local & 31;
        const float* W = (z == 0) ? W0 : (z == 1) ? W1 : (z == 2) ? W2 : W3;
        f16* dst = Wt + (size_t)z * HIDDEN * HIDDEN;
        const int k0 = by * 32, n0 = bx * 32;
        {
            const int r = t >> 3, c4 = (t & 7) * 4;
            const float4 u = *(const float4*)(W + (size_t)(k0 + r) * HIDDEN + n0 + c4);
            ts[r][c4 + 0] = u.x; ts[r][c4 + 1] = u.y; ts[r][c4 + 2] = u.z; ts[r][c4 + 3] = u.w;
        }
        __syncthreads();
        {
            const int r = t >> 3, c4 = (t & 7) * 4;
            f16* o = dst + (size_t)(n0 + r) * HIDDEN + k0 + c4;
            o[0] = (f16)ts[c4 + 0][r]; o[1] = (f16)ts[c4 + 1][r];
            o[2] = (f16)ts[c4 + 2][r]; o[3] = (f16)ts[c4 + 3][r];
        }
        return;
    }
    {
        const int local = bid - 6144;          // [0,128): y=local>>2 in [0,32), x=local&3
        const int k0 = (local >> 2) * 32, p0 = (local & 3) * 32;
        {
            const int r = t >> 3, c4 = (t & 7) * 4;
            const float4 u = *(const float4*)(rW1 + (size_t)(k0 + r) * POS_DIM + p0 + c4);
            ts[r][c4 + 0] = u.x; ts[r][c4 + 1] = u.y; ts[r][c4 + 2] = u.z; ts[r][c4 + 3] = u.w;
        }
        __syncthreads();
        {
            const int r = t >> 3, c4 = (t & 7) * 4;
            f16* oh = Wh + (size_t)(p0 + r) * HIDDEN + k0 + c4;
            f16* ol = Wl + (size_t)(p0 + r) * HIDDEN + k0 + c4;
#pragma unroll
            for (int u = 0; u < 4; ++u) {
                const float v = ts[c4 + u][r];
                const f16 hi = (f16)v;
                oh[u] = hi;
                ol[u] = (f16)(v - (float)hi);
            }
        }
    }
}

// ---------------------------------------------------------------------------
// m97-style f16 MFMA GEMM: C[4096][N] = A[4096][1024] @ Bt[N][1024]^T.
// r9-proven operand SWAP epilogue: mfma(bf, af) -> D register dim runs along
// N -> vectorized f16x4/f32x4 stores, bitwise-identical C.
// ---------------------------------------------------------------------------
__global__ __launch_bounds__(256, 3) void gemm_gll(const f16* __restrict__ A,
                                                   const f16* __restrict__ Bt,
                                                   f16* __restrict__ Cb,
                                                   float* __restrict__ Cf,
                                                   int N, int f16out) {
    __shared__ __align__(16) f16 As[128 * 64];  // [row][slot*8], slot = seg ^ (row&7)
    __shared__ __align__(16) f16 Bs[128 * 64];
    const int tid = threadIdx.x;
    const int w = tid >> 6, lane = tid & 63;
    const int g = lane >> 4, c = lane & 15;
    const int m0 = blockIdx.y * 128, n0 = blockIdx.x * 128;
    const int wm = (w & 1) * 64, wn = (w >> 1) * 64;

    const int lrow = lane >> 3;            // 0..7
    const int lseg = (lane & 7) ^ lrow;    // XOR swizzle on global k-segment
    const f16* gA = A + (size_t)(m0 + w * 32 + lrow) * 1024 + lseg * 8;
    const f16* gB = Bt + (size_t)(n0 + w * 32 + lrow) * 1024 + lseg * 8;
    f16* lA = &As[(w * 32) * 64];
    f16* lB = &Bs[(w * 32) * 64];

    f32x4 acc[4][4];
    const f32x4 z = {0.f, 0.f, 0.f, 0.f};
#pragma unroll
    for (int i = 0; i < 4; ++i)
#pragma unroll
        for (int j = 0; j < 4; ++j) acc[i][j] = z;

    const int rsw = c & 7;
    for (int k0 = 0; k0 < 1024; k0 += 64) {
        __syncthreads();
#pragma unroll
        for (int p = 0; p < 4; ++p) {
            glds16(gA + (size_t)p * 8 * 1024 + k0, lA + p * 8 * 64);
            glds16(gB + (size_t)p * 8 * 1024 + k0, lB + p * 8 * 64);
        }
        __syncthreads();
#pragma unroll
        for (int s = 0; s < 2; ++s) {
            f16x8 af[4], bf[4];
#pragma unroll
            for (int i = 0; i < 4; ++i)
                af[i] = *(const f16x8*)&As[(wm + i * 16 + c) * 64 + (((s * 4 + g) ^ rsw) * 8)];
#pragma unroll
            for (int j = 0; j < 4; ++j)
                bf[j] = *(const f16x8*)&Bs[(wn + j * 16 + c) * 64 + (((s * 4 + g) ^ rsw) * 8)];
#pragma unroll
            for (int i = 0; i < 4; ++i)
#pragma unroll
                for (int j = 0; j < 4; ++j)
                    acc[i][j] = __builtin_amdgcn_mfma_f32_16x16x32_f16(bf[j], af[i], acc[i][j], 0, 0, 0);
        }
    }
    // swapped D-layout: acc[i][j][r] = C[m0+wm+i*16+c][n0+wn+j*16+4g+r]
#pragma unroll
    for (int i = 0; i < 4; ++i)
#pragma unroll
        for (int j = 0; j < 4; ++j) {
            const size_t off = (size_t)(m0 + wm + i * 16 + c) * N + n0 + wn + j * 16 + 4 * g;
            if (f16out) {
                f16x4 v = {(f16)acc[i][j][0], (f16)acc[i][j][1],
                           (f16)acc[i][j][2], (f16)acc[i][j][3]};
                *(f16x4*)(Cb + off) = v;
            } else {
                *(f32x4*)(Cf + off) = acc[i][j];
            }
        }
}

// ---------------------------------------------------------------------------
// BM=64 variant for the OUT projection (f32 out only). The 128-tile version
// at M=4096,N=1024 gives grid 256 = 1 block/CU: every K-step drain fully
// exposed, no co-resident block (r7 lesson). 64x128 tiles -> grid (8,64) =
// 512 blocks = 2/CU, LDS 24 KB. Same K-step order + operand-swap epilogue ->
// bitwise-identical C. Swizzle invariants preserved: write row&7 = lrow,
// read row&7 = c&7.
// ---------------------------------------------------------------------------
__global__ __launch_bounds__(256, 4) void gemm_gll64(const f16* __restrict__ A,
                                                     const f16* __restrict__ Bt,
                                                     float* __restrict__ Cf,
                                                     int N) {
    __shared__ __align__(16) f16 As[64 * 64];   // 8 KB
    __shared__ __align__(16) f16 Bs[128 * 64];  // 16 KB
    const int tid = threadIdx.x;
    const int w = tid >> 6, lane = tid & 63;
    const int g = lane >> 4, c = lane & 15;
    const int m0 = blockIdx.y * 64, n0 = blockIdx.x * 128;
    const int wm = (w & 1) * 32, wn = (w >> 1) * 64;

    const int lrow = lane >> 3;            // 0..7
    const int lseg = (lane & 7) ^ lrow;    // XOR swizzle on global k-segment
    const f16* gA = A + (size_t)(m0 + w * 16 + lrow) * 1024 + lseg * 8;
    const f16* gB = Bt + (size_t)(n0 + w * 32 + lrow) * 1024 + lseg * 8;
    f16* lA = &As[(w * 16) * 64];
    f16* lB = &Bs[(w * 32) * 64];

    f32x4 acc[2][4];
    const f32x4 z = {0.f, 0.f, 0.f, 0.f};
#pragma unroll
    for (int i = 0; i < 2; ++i)
#pragma unroll
        for (int j = 0; j < 4; ++j) acc[i][j] = z;

    const int rsw = c & 7;
    for (int k0 = 0; k0 < 1024; k0 += 64) {
        __syncthreads();
#pragma unroll
        for (int p = 0; p < 2; ++p)
            glds16(gA + (size_t)p * 8 * 1024 + k0, lA + p * 8 * 64);
#pragma unroll
        for (int p = 0; p < 4; ++p)
            glds16(gB + (size_t)p * 8 * 1024 + k0, lB + p * 8 * 64);
        __syncthreads();
#pragma unroll
        for (int s = 0; s < 2; ++s) {
            f16x8 af[2], bf[4];
#pragma unroll
            for (int i = 0; i < 2; ++i)
                af[i] = *(const f16x8*)&As[(wm + i * 16 + c) * 64 + (((s * 4 + g) ^ rsw) * 8)];
#pragma unroll
            for (int j = 0; j < 4; ++j)
                bf[j] = *(const f16x8*)&Bs[(wn + j * 16 + c) * 64 + (((s * 4 + g) ^ rsw) * 8)];
#pragma unroll
            for (int i = 0; i < 2; ++i)
#pragma unroll
                for (int j = 0; j < 4; ++j)
                    acc[i][j] = __builtin_amdgcn_mfma_f32_16x16x32_f16(bf[j], af[i], acc[i][j], 0, 0, 0);
        }
    }
#pragma unroll
    for (int i = 0; i < 2; ++i)
#pragma unroll
        for (int j = 0; j < 4; ++j) {
            const size_t off = (size_t)(m0 + wm + i * 16 + c) * N + n0 + wn + j * 16 + 4 * g;
            *(f32x4*)(Cf + off) = acc[i][j];
        }
}

// ---------------------------------------------------------------------------
// RePo MLP via split-f16 MFMA
// ---------------------------------------------------------------------------
__device__ __forceinline__ float gelu_tanh(float x) {
    const float kA = 0.7978845608028654f;
    return 0.5f * x * (1.0f + tanhf(kA * (x + 0.044715f * x * x * x)));
}

__global__ __launch_bounds__(256, 2) void repo_mfma(const float* __restrict__ x,
                                                    const f16* __restrict__ w1h,
                                                    const f16* __restrict__ w1l,
                                                    const float* __restrict__ b1,
                                                    const float* __restrict__ W2,
                                                    const float* __restrict__ b2,
                                                    float* __restrict__ raw) {
    __shared__ __align__(16) f16 Ash[64 * 32], Asl[64 * 32];
    __shared__ __align__(16) f16 Bsh[128 * 32], Bsl[128 * 32];
    __shared__ float red[4][64];
    const int tid = threadIdx.x;
    const int w = tid >> 6, lane = tid & 63;
    const int g = lane >> 4, c = lane & 15;
    const int m0 = blockIdx.x * 64;

    const int arow = tid >> 2, aseg = tid & 3;
    const int aslot = (aseg ^ ((arow ^ (arow >> 2)) & 3)) << 3;
    const float* gA = x + (size_t)(m0 + arow) * 1024 + aseg * 8;
    const f16* gBh0 = w1h + (size_t)arow * 1024 + aseg * 8;
    const f16* gBh1 = w1h + (size_t)(arow + 64) * 1024 + aseg * 8;
    const f16* gBl0 = w1l + (size_t)arow * 1024 + aseg * 8;
    const f16* gBl1 = w1l + (size_t)(arow + 64) * 1024 + aseg * 8;
    f16* sAh = &Ash[arow * 32 + aslot];
    f16* sAl = &Asl[arow * 32 + aslot];
    f16* sBh0 = &Bsh[arow * 32 + aslot];
    f16* sBh1 = &Bsh[(arow + 64) * 32 + aslot];
    f16* sBl0 = &Bsl[arow * 32 + aslot];
    f16* sBl1 = &Bsl[(arow + 64) * 32 + aslot];

    const int foff = ((g ^ ((c ^ (c >> 2)) & 3)) << 3);

    f32x4 acc[4][2];
    const f32x4 z = {0.f, 0.f, 0.f, 0.f};
#pragma unroll
    for (int i = 0; i < 4; ++i) { acc[i][0] = z; acc[i][1] = z; }

    float4 pa0 = *(const float4*)gA;
    float4 pa1 = *(const float4*)(gA + 4);
    f16x8 pbh0 = *(const f16x8*)gBh0, pbh1 = *(const f16x8*)gBh1;
    f16x8 pbl0 = *(const f16x8*)gBl0, pbl1 = *(const f16x8*)gBl1;

    for (int k0 = 0; k0 < 1024; k0 += 32) {
        __syncthreads();
        {
            const float av[8] = {pa0.x, pa0.y, pa0.z, pa0.w, pa1.x, pa1.y, pa1.z, pa1.w};
            f16x8 ah, al;
#pragma unroll
            for (int u = 0; u < 8; ++u) {
                const f16 hi = (f16)av[u];
                ah[u] = hi;
                al[u] = (f16)(av[u] - (float)hi);
            }
            *(f16x8*)sAh = ah; *(f16x8*)sAl = al;
            *(f16x8*)sBh0 = pbh0; *(f16x8*)sBh1 = pbh1;
            *(f16x8*)sBl0 = pbl0; *(f16x8*)sBl1 = pbl1;
        }
        __syncthreads();
        if (k0 + 32 < 1024) {
            pa0 = *(const float4*)(gA + k0 + 32);
            pa1 = *(const float4*)(gA + k0 + 36);
            pbh0 = *(const f16x8*)(gBh0 + k0 + 32);
            pbh1 = *(const f16x8*)(gBh1 + k0 + 32);
            pbl0 = *(const f16x8*)(gBl0 + k0 + 32);
            pbl1 = *(const f16x8*)(gBl1 + k0 + 32);
        }
        f16x8 ah[4], al[4], bh[2], bl[2];
#pragma unroll
        for (int i = 0; i < 4; ++i) {
            ah[i] = *(const f16x8*)&Ash[(i * 16 + c) * 32 + foff];
            al[i] = *(const f16x8*)&Asl[(i * 16 + c) * 32 + foff];
        }
#pragma unroll
        for (int j = 0; j < 2; ++j) {
            bh[j] = *(const f16x8*)&Bsh[(w * 32 + j * 16 + c) * 32 + foff];
            bl[j] = *(const f16x8*)&Bsl[(w * 32 + j * 16 + c) * 32 + foff];
        }
#pragma unroll
        for (int i = 0; i < 4; ++i)
#pragma unroll
            for (int j = 0; j < 2; ++j) {
                acc[i][j] = __builtin_amdgcn_mfma_f32_16x16x32_f16(ah[i], bh[j], acc[i][j], 0, 0, 0);
                acc[i][j] = __builtin_amdgcn_mfma_f32_16x16x32_f16(ah[i], bl[j], acc[i][j], 0, 0, 0);
                acc[i][j] = __builtin_amdgcn_mfma_f32_16x16x32_f16(al[i], bh[j], acc[i][j], 0, 0, 0);
            }
    }
    float b1v[2], w2v[2];
#pragma unroll
    for (int j = 0; j < 2; ++j) {
        const int col = w * 32 + j * 16 + c;
        b1v[j] = b1[col];
        w2v[j] = W2[col];
    }
    float part[4][4];
#pragma unroll
    for (int i = 0; i < 4; ++i)
#pragma unroll
        for (int r = 0; r < 4; ++r) {
            float s = 0.f;
#pragma unroll
            for (int j = 0; j < 2; ++j)
                s += gelu_tanh(acc[i][j][r] + b1v[j]) * w2v[j];
            s += __shfl_xor(s, 1, 64);
            s += __shfl_xor(s, 2, 64);
            s += __shfl_xor(s, 4, 64);
            s += __shfl_xor(s, 8, 64);
            part[i][r] = s;
        }
    if (c == 0)
#pragma unroll
        for (int i = 0; i < 4; ++i)
#pragma unroll
            for (int r = 0; r < 4; ++r)
                red[w][i * 16 + 4 * g + r] = part[i][r];
    __syncthreads();
    if (tid < 64)
        raw[m0 + tid] = red[0][tid] + red[1][tid] + red[2][tid] + red[3][tid] + b2[0];
}

__device__ __forceinline__ double softplus_d(double x) {
    return (x > 0.0) ? x + log1p(exp(-x)) : log1p(exp(x));
}

__global__ __launch_bounds__(256) void repo_cumsum_kernel(const float* __restrict__ raw,
                                                          float* __restrict__ pos) {
    __shared__ double bufA[256];
    __shared__ double bufB[256];
    const int b = blockIdx.x;
    const int t = threadIdx.x;
    const float* r = raw + (size_t)b * SEQ;

    double loc[8];
    double sum = 0.0;
#pragma unroll
    for (int i = 0; i < 8; ++i) {
        sum += softplus_d((double)r[t * 8 + i]);
        loc[i] = sum;
    }
    bufA[t] = sum;
    __syncthreads();

    double* src = bufA;
    double* dst = bufB;
    for (int off = 1; off < 256; off <<= 1) {
        double v = src[t];
        if (t >= off) v += src[t - off];
        dst[t] = v;
        __syncthreads();
        double* tmp = src; src = dst; dst = tmp;
    }
    const double excl = src[t] - sum;
#pragma unroll
    for (int i = 0; i < 8; ++i)
        pos[(size_t)b * SEQ + t * 8 + i] = (float)(excl + loc[i]);
}

// ---------------------------------------------------------------------------
// cos/sin table [tok][32]
// ---------------------------------------------------------------------------
__global__ __launch_bounds__(256) void sctab_kernel(const float* __restrict__ pos,
                                                    float* __restrict__ costab,
                                                    float* __restrict__ sintab) {
    const int idx = blockIdx.x * 256 + threadIdx.x;
    const int tok = idx >> 5, i = idx & 31;
    const double ang = (double)pos[tok] * exp(-(double)i * 0.28782313662425574);
    double sa, ca;
    sincos(ang, &sa, &ca);
    costab[idx] = (float)ca;
    sintab[idx] = (float)sa;
}

// ---------------------------------------------------------------------------
// Pack K (rope fused) + V into fragment-major layouts; rope Q in-place.
// Proven r7/r2 layouts: K frag f16x8 at frag*512+lane*8; V frag f16x4 at
// frag*256+lane*4.
// ---------------------------------------------------------------------------
__global__ __launch_bounds__(256) void packkv_kernel(f16* __restrict__ qkv,
                                                     const float* __restrict__ costab,
                                                     const float* __restrict__ sintab,
                                                     f16* __restrict__ kfo,
                                                     f16* __restrict__ vfo) {
    __shared__ __align__(16) f16 kds[64][72];
    __shared__ __align__(16) f16 vds[64][72];
    const int t = threadIdx.x;
    const int s0 = blockIdx.x * 64;
    const int h = blockIdx.y, b = blockIdx.z;
    const int key = t >> 2, part = t & 3;
    const int tok = b * SEQ + s0 + key;
    {
        float cs[8], sn[8];
        *(float4*)cs       = *(const float4*)(costab + tok * 32 + part * 8);
        *(float4*)(cs + 4) = *(const float4*)(costab + tok * 32 + part * 8 + 4);
        *(float4*)sn       = *(const float4*)(sintab + tok * 32 + part * 8);
        *(float4*)(sn + 4) = *(const float4*)(sintab + tok * 32 + part * 8 + 4);
        f16* qrow = qkv + (size_t)tok * 3072 + h * HEAD_DIM;
        {
            f16x8 lo = *(const f16x8*)(qrow + part * 8);
            f16x8 hi = *(const f16x8*)(qrow + part * 8 + 32);
#pragma unroll
            for (int u = 0; u < 8; ++u) {
                const float l = (float)lo[u], hh = (float)hi[u];
                lo[u] = (f16)(l * cs[u] - hh * sn[u]);
                hi[u] = (f16)(l * sn[u] + hh * cs[u]);
            }
            *(f16x8*)(qrow + part * 8) = lo;
            *(f16x8*)(qrow + part * 8 + 32) = hi;
        }
        const f16* krow = qrow + 1024;
        {
            f16x8 lo = *(const f16x8*)(krow + part * 8);
            f16x8 hi = *(const f16x8*)(krow + part * 8 + 32);
#pragma unroll
            for (int u = 0; u < 8; ++u) {
                const float l = (float)lo[u], hh = (float)hi[u];
                kds[key][part * 8 + u]      = (f16)(l * cs[u] - hh * sn[u]);
                kds[key][32 + part * 8 + u] = (f16)(l * sn[u] + hh * cs[u]);
            }
        }
        const f16* vrow = qrow + 2048;
        f16x8 v0 = *(const f16x8*)(vrow + part * 16);
        f16x8 v1 = *(const f16x8*)(vrow + part * 16 + 8);
#pragma unroll
        for (int u = 0; u < 8; ++u) {
            vds[part * 16 + u][key] = v0[u];
            vds[part * 16 + 8 + u][key] = v1[u];
        }
    }
    __syncthreads();
    const size_t cb = ((size_t)((b * HEADS + h) * 32) + blockIdx.x) * 4096;
#pragma unroll
    for (int p = 0; p < 2; ++p) {
        const int idx = p * 256 + t;
        const int frag = idx >> 6, lane = idx & 63;
        const int jn = frag >> 1, half = frag & 1, g = lane >> 4, c = lane & 15;
        *(f16x8*)(kfo + cb + frag * 512 + lane * 8) =
            *(const f16x8*)(&kds[jn * 16 + c][half * 32 + g * 8]);
    }
#pragma unroll
    for (int p = 0; p < 4; ++p) {
        const int idx = p * 256 + t;
        const int frag = idx >> 6, lane = idx & 63;
        const int jd = frag >> 2, jn = frag & 3, g = lane >> 4, c = lane & 15;
        *(f16x4*)(vfo + cb + frag * 256 + lane * 4) =
            *(const f16x4*)(&vds[jd * 16 + c][jn * 16 + 4 * g]);
    }
}

// ---------------------------------------------------------------------------
// MFMA flash attention, no split-K (r7/r9 structure) with T14 reg-staging
// (r10: flat vs glds16 but marginally faster; kept). attn line is CLOSED:
// r1/r3/r4/r5/r8/r10 all confirmed this loop as the local optimum (~54us);
// the residual ~20% dead time is barrier skew intrinsic to the 2-barrier,
// 2-block/CU structure, not load latency (T14 null proved that).
// ---------------------------------------------------------------------------
__global__ __launch_bounds__(256, 2) void attn_f16(const f16* __restrict__ qkv,
                                                   const f16* __restrict__ kfr,
                                                   const f16* __restrict__ vfr,
                                                   f16* __restrict__ aof0) {
    __shared__ __align__(16) f16 kls[4096];     // one K chunk (8 KB)
    __shared__ __align__(16) f16 vls[4096];     // one V chunk (8 KB)
    __shared__ __align__(16) f16 ot[4][32][72]; // epilogue transpose (18 KB)
    const int tid = threadIdx.x;
    const int w = tid >> 6, lane = tid & 63;
    const int g = lane >> 4, c = lane & 15;

    // XCD-aware decode: wid -> (xcd, slot) -> (combo=(h,b), xblk)
    const int wid = blockIdx.x;                 // 0..511
    const int xcd = wid & 7, slot = wid >> 3;   // slot 0..63
    const int combo = xcd * 4 + (slot >> 4);    // 0..31: 4 (h,b) combos/XCD
    const int xblk = slot & 15;                 // 0..15
    const int h = combo & 15;
    const int b = combo >> 4;

    const int bh = b * HEADS + h;
    const int row0 = xblk * 128 + w * 32;

    const f16* qb = qkv + (size_t)(b * SEQ + row0) * 3072 + h * HEAD_DIM + g * 8;
    // per-thread staging addresses (wave w owns bytes [w*2KB, w*2KB+2KB))
    const f16* kfb = kfr + (size_t)bh * 32 * 4096 + w * 1024 + lane * 8;
    const f16* vfb = vfr + (size_t)bh * 32 * 4096 + w * 1024 + lane * 8;
    f16* kd = kls + w * 1024 + lane * 8;
    f16* vd = vls + w * 1024 + lane * 8;

    f16x8 qf[2][2];
#pragma unroll
    for (int i = 0; i < 2; ++i) {
        qf[i][0] = *(const f16x8*)(qb + (size_t)(i * 16 + c) * 3072);
        qf[i][1] = *(const f16x8*)(qb + (size_t)(i * 16 + c) * 3072 + 32);
    }
    const f32x4 z = {0.f, 0.f, 0.f, 0.f};
    f32x4 acc[4][2];
#pragma unroll
    for (int jd = 0; jd < 4; ++jd) { acc[jd][0] = z; acc[jd][1] = z; }
    float dloc[2] = {0.f, 0.f};   // denominator partials (VALU pipe)

    const float SC = 0.125f * 1.4426950408889634f;

    // prologue: chunk 0 -> regs
    f16x8 kr0 = *(const f16x8*)(kfb);
    f16x8 kr1 = *(const f16x8*)(kfb + 512);
    f16x8 vr0 = *(const f16x8*)(vfb);
    f16x8 vr1 = *(const f16x8*)(vfb + 512);

    for (int cc = 0; cc < 32; ++cc) {
        __syncthreads();   // prior chunk's ds_reads done; staging regs landed
        *(f16x8*)kd         = kr0;
        *(f16x8*)(kd + 512) = kr1;
        *(f16x8*)vd         = vr0;
        *(f16x8*)(vd + 512) = vr1;
        __syncthreads();   // ds_writes visible block-wide
        if (cc + 1 < 32) {
            // issue next chunk's loads AFTER the barrier: they stay in flight
            // across the whole compute phase (no exposed latency)
            const f16* kg = kfb + (size_t)(cc + 1) * 4096;
            const f16* vg = vfb + (size_t)(cc + 1) * 4096;
            kr0 = *(const f16x8*)(kg);
            kr1 = *(const f16x8*)(kg + 512);
            vr0 = *(const f16x8*)(vg);
            vr1 = *(const f16x8*)(vg + 512);
        }

        f16x8 kf[8];
        f16x4 vf[16];
#pragma unroll
        for (int f = 0; f < 8; ++f) kf[f] = *(const f16x8*)(kls + lane * 8 + f * 512);
#pragma unroll
        for (int f = 0; f < 16; ++f) vf[f] = *(const f16x4*)(vls + lane * 4 + f * 256);

#pragma unroll
        for (int i = 0; i < 2; ++i) {
            f32x4 s[4];
#pragma unroll
            for (int jn = 0; jn < 4; ++jn) {
                s[jn] = __builtin_amdgcn_mfma_f32_16x16x32_f16(kf[jn * 2], qf[i][0], z, 0, 0, 0);
                s[jn] = __builtin_amdgcn_mfma_f32_16x16x32_f16(kf[jn * 2 + 1], qf[i][1], s[jn], 0, 0, 0);
            }
#pragma unroll
            for (int jn = 0; jn < 4; ++jn) {
                const float e0 = __builtin_amdgcn_exp2f(fmaf(s[jn][0], SC, -8.0f));
                const float e1 = __builtin_amdgcn_exp2f(fmaf(s[jn][1], SC, -8.0f));
                const float e2 = __builtin_amdgcn_exp2f(fmaf(s[jn][2], SC, -8.0f));
                const float e3 = __builtin_amdgcn_exp2f(fmaf(s[jn][3], SC, -8.0f));
                dloc[i] += (e0 + e1) + (e2 + e3);
                f16x4 pf = {(f16)e0, (f16)e1, (f16)e2, (f16)e3};
#pragma unroll
                for (int jd = 0; jd < 4; ++jd)
                    acc[jd][i] = __builtin_amdgcn_mfma_f32_16x16x16f16(vf[jd * 4 + jn], pf, acc[jd][i], 0, 0, 0);
            }
        }
    }

    // denominators: reduce across the 4 g-groups (lanes c, 16+c, 32+c, 48+c);
    // after the two xors every lane holds the full sum for its query (i, c).
    float inv[2];
#pragma unroll
    for (int i = 0; i < 2; ++i) {
        dloc[i] += __shfl_xor(dloc[i], 16, 64);
        dloc[i] += __shfl_xor(dloc[i], 32, 64);
        inv[i] = 1.0f / dloc[i];   // 2^-8 bias cancels between num and denom
    }

    // numerator: normalize in f32, O^T regs -> wave-private LDS transpose ->
    // coalesced f16 store (single output, no combine pass)
    __syncthreads();   // all ds_reads of the last chunk done before ot reuse
#pragma unroll
    for (int i = 0; i < 2; ++i)
#pragma unroll
        for (int jd = 0; jd < 4; ++jd)
#pragma unroll
            for (int r = 0; r < 4; ++r)
                ot[w][i * 16 + c][jd * 16 + 4 * g + r] = (f16)(acc[jd][i][r] * inv[i]);
    const int tr = lane >> 1, hf = lane & 1;
    f16* aob = aof0 + (size_t)(b * SEQ + row0 + tr) * HIDDEN + h * HEAD_DIM + hf * 32;
#pragma unroll
    for (int q = 0; q < 4; ++q)
        *(f16x8*)(aob + q * 8) = *(const f16x8*)(&ot[w][tr][hf * 32 + q * 8]);
}

// ---------------------------------------------------------------------------
// launch
// ---------------------------------------------------------------------------
extern "C" void kernel_launch(void* const* d_in, const int* in_sizes, int n_in,
                              void* d_out, int out_size, void* d_ws, size_t ws_size,
                              hipStream_t stream) {
    const float* x   = (const float*)d_in[0];
    const float* W_q = (const float*)d_in[1];
    const float* W_k = (const float*)d_in[2];
    const float* W_v = (const float*)d_in[3];
    const float* W_o = (const float*)d_in[4];
    const float* rW1 = (const float*)d_in[5];
    const float* rb1 = (const float*)d_in[6];
    const float* rW2 = (const float*)d_in[7];
    const float* rb2 = (const float*)d_in[8];
    float* out = (float*)d_out;

    const size_t MAT = (size_t)TOKENS * HIDDEN;   // 4M
    const size_t WSZ = (size_t)HIDDEN * HIDDEN;   // 1M
    f16* x16  = (f16*)d_ws;
    f16* wqkv = x16 + MAT;            // [3072][1024]; wot contiguous after
    f16* wot  = wqkv + 3 * WSZ;
    f16* qkv  = wot + WSZ;            // [4096][3072]
    f16* kfr  = qkv + 3 * MAT;
    f16* vfr  = kfr + MAT;
    f16* aof0 = vfr + MAT;
    f16* aof1 = aof0 + MAT;           // unused (no split-K)
    f16* w1h  = aof1 + MAT;           // [128][1024]
    f16* w1l  = w1h + POS_DIM * HIDDEN;
    float* raw    = (float*)(w1l + POS_DIM * HIDDEN);
    float* pos    = raw + TOKENS;
    float* costab = pos + TOKENS;
    float* sintab = costab + TOKENS * 32;

    // merged preprocessing: cast_x (2048) + cast_wt4 (4096) + cast_w1t (128)
    cast_all_kernel<<<6272, 256, 0, stream>>>(x, W_q, W_k, W_v, W_o, rW1,
                                              x16, wqkv, w1h, w1l);

    gemm_gll<<<dim3(24, 32), 256, 0, stream>>>(x16, wqkv, qkv, nullptr, 3072, 1);

    repo_mfma<<<64, 256, 0, stream>>>(x, w1h, w1l, rb1, rW2, rb2, raw);
    repo_cumsum_kernel<<<BATCH, 256, 0, stream>>>(raw, pos);
    sctab_kernel<<<TOKENS * 32 / 256, 256, 0, stream>>>(pos, costab, sintab);

    packkv_kernel<<<dim3(SEQ / 64, HEADS, BATCH), 256, 0, stream>>>(qkv, costab, sintab, kfr, vfr);

    attn_f16<<<dim3(512), 256, 0, stream>>>(qkv, kfr, vfr, aof0);

    // out projection: BM=64 tiles -> grid (8,64) = 512 blocks = 2/CU
    gemm_gll64<<<dim3(8, 64), 256, 0, stream>>>(aof0, wot, out, 1024);
}

// Round 12
// 219.394 us; speedup vs baseline: 1.1670x; 1.0929x over previous
//
#include <hip/hip_runtime.h>
#include <hip/hip_bf16.h>
#include <math.h>

#define HIDDEN 1024
#define HEADS 16
#define HEAD_DIM 64
#define POS_DIM 128
#define BATCH 2
#define SEQ 2048
#define TOKENS (BATCH * SEQ)

typedef _Float16 f16;
typedef __attribute__((ext_vector_type(8))) _Float16 f16x8;
typedef __attribute__((ext_vector_type(4))) _Float16 f16x4;
typedef __attribute__((ext_vector_type(4))) float f32x4;

// async global->LDS, 16B per lane; LDS dest = wave-uniform base + lane*16
__device__ __forceinline__ void glds16(const f16* g, f16* l) {
    __builtin_amdgcn_global_load_lds((const __attribute__((address_space(1))) unsigned int*)g,
                                     (__attribute__((address_space(3))) unsigned int*)l, 16, 0, 0);
}

// ---------------------------------------------------------------------------
// MERGED preprocessing (1 launch): block-uniform dispatch on bid.
//   [0, 2048)        : cast x fp32->f16, 8 elems/thread
//   [2048, 6144)     : 4 weights [1024][1024] -> Wt f16 transposed
//   [6144, 6272)     : W1 [1024][128] -> w1t hi/lo split transposed
// ---------------------------------------------------------------------------
__global__ __launch_bounds__(256) void cast_all_kernel(const float* __restrict__ x,
                                                       const float* __restrict__ W0,
                                                       const float* __restrict__ W1,
                                                       const float* __restrict__ W2,
                                                       const float* __restrict__ W3,
                                                       const float* __restrict__ rW1,
                                                       f16* __restrict__ x16,
                                                       f16* __restrict__ Wt,
                                                       f16* __restrict__ Wh,
                                                       f16* __restrict__ Wl) {
    __shared__ float ts[32][33];
    const int bid = blockIdx.x;
    const int t = threadIdx.x;
    if (bid < 2048) {
        const int i = (bid * 256 + t) * 8;
        const float4 u = *(const float4*)(x + i);
        const float4 v = *(const float4*)(x + i + 4);
        f16x8 r = {(f16)u.x, (f16)u.y, (f16)u.z, (f16)u.w,
                   (f16)v.x, (f16)v.y, (f16)v.z, (f16)v.w};
        *(f16x8*)(x16 + i) = r;
        return;
    }
    if (bid < 6144) {
        const int local = bid - 2048;
        const int z = local >> 10;
        const int by = (local & 1023) >> 5, bx = local & 31;
        const float* W = (z == 0) ? W0 : (z == 1) ? W1 : (z == 2) ? W2 : W3;
        f16* dst = Wt + (size_t)z * HIDDEN * HIDDEN;
        const int k0 = by * 32, n0 = bx * 32;
        {
            const int r = t >> 3, c4 = (t & 7) * 4;
            const float4 u = *(const float4*)(W + (size_t)(k0 + r) * HIDDEN + n0 + c4);
            ts[r][c4 + 0] = u.x; ts[r][c4 + 1] = u.y; ts[r][c4 + 2] = u.z; ts[r][c4 + 3] = u.w;
        }
        __syncthreads();
        {
            const int r = t >> 3, c4 = (t & 7) * 4;
            f16* o = dst + (size_t)(n0 + r) * HIDDEN + k0 + c4;
            o[0] = (f16)ts[c4 + 0][r]; o[1] = (f16)ts[c4 + 1][r];
            o[2] = (f16)ts[c4 + 2][r]; o[3] = (f16)ts[c4 + 3][r];
        }
        return;
    }
    {
        const int local = bid - 6144;          // [0,128): y=local>>2 in [0,32), x=local&3
        const int k0 = (local >> 2) * 32, p0 = (local & 3) * 32;
        {
            const int r = t >> 3, c4 = (t & 7) * 4;
            const float4 u = *(const float4*)(rW1 + (size_t)(k0 + r) * POS_DIM + p0 + c4);
            ts[r][c4 + 0] = u.x; ts[r][c4 + 1] = u.y; ts[r][c4 + 2] = u.z; ts[r][c4 + 3] = u.w;
        }
        __syncthreads();
        {
            const int r = t >> 3, c4 = (t & 7) * 4;
            f16* oh = Wh + (size_t)(p0 + r) * HIDDEN + k0 + c4;
            f16* ol = Wl + (size_t)(p0 + r) * HIDDEN + k0 + c4;
#pragma unroll
            for (int u = 0; u < 4; ++u) {
                const float v = ts[c4 + u][r];
                const f16 hi = (f16)v;
                oh[u] = hi;
                ol[u] = (f16)(v - (float)hi);
            }
        }
    }
}

__device__ __forceinline__ float gelu_tanh(float x) {
    const float kA = 0.7978845608028654f;
    return 0.5f * x * (1.0f + tanhf(kA * (x + 0.044715f * x * x * x)));
}

// ---------------------------------------------------------------------------
// FUSED qkv-GEMM + RePo-MLP (1 launch, was 2). repo_mfma ran on 64 blocks =
// 0.25 blocks/CU -- 75% of the GPU idle for its whole serial slot, and it
// depends only on x, not on the GEMM. Merged: bid<64 -> repo path (dispatched
// FIRST so the long blocks start immediately); bid>=64 -> gemm path (flat
// 24x32, N=3072, f16 out). LDS via union (32KB gemm / 25KB repo). Both paths
// byte-identical to the proven kernels -> bitwise-identical outputs; only
// scheduling changes. Blocks fully independent: no new sync structure.
// ---------------------------------------------------------------------------
union SmemPool {
    struct { f16 As[128 * 64]; f16 Bs[128 * 64]; } g;                    // 32 KB
    struct { f16 Ash[64 * 32]; f16 Asl[64 * 32];
             f16 Bsh[128 * 32]; f16 Bsl[128 * 32]; float red[4][64]; } r; // 25 KB
};

__global__ __launch_bounds__(256, 2) void gemm_repo_kernel(
        const f16* __restrict__ A, const f16* __restrict__ Bt, f16* __restrict__ Cb,
        const float* __restrict__ x,
        const f16* __restrict__ w1h, const f16* __restrict__ w1l,
        const float* __restrict__ b1, const float* __restrict__ W2,
        const float* __restrict__ b2, float* __restrict__ raw) {
    __shared__ __align__(16) SmemPool sp;
    const int bid = blockIdx.x;
    const int tid = threadIdx.x;
    const int w = tid >> 6, lane = tid & 63;
    const int g = lane >> 4, c = lane & 15;

    if (bid < 64) {
        // ---------------- repo path (byte-identical math to repo_mfma) ----
        f16* Ash = sp.r.Ash; f16* Asl = sp.r.Asl;
        f16* Bsh = sp.r.Bsh; f16* Bsl = sp.r.Bsl;
        float (*red)[64] = sp.r.red;
        const int m0 = bid * 64;

        const int arow = tid >> 2, aseg = tid & 3;
        const int aslot = (aseg ^ ((arow ^ (arow >> 2)) & 3)) << 3;
        const float* gA = x + (size_t)(m0 + arow) * 1024 + aseg * 8;
        const f16* gBh0 = w1h + (size_t)arow * 1024 + aseg * 8;
        const f16* gBh1 = w1h + (size_t)(arow + 64) * 1024 + aseg * 8;
        const f16* gBl0 = w1l + (size_t)arow * 1024 + aseg * 8;
        const f16* gBl1 = w1l + (size_t)(arow + 64) * 1024 + aseg * 8;
        f16* sAh = &Ash[arow * 32 + aslot];
        f16* sAl = &Asl[arow * 32 + aslot];
        f16* sBh0 = &Bsh[arow * 32 + aslot];
        f16* sBh1 = &Bsh[(arow + 64) * 32 + aslot];
        f16* sBl0 = &Bsl[arow * 32 + aslot];
        f16* sBl1 = &Bsl[(arow + 64) * 32 + aslot];

        const int foff = ((g ^ ((c ^ (c >> 2)) & 3)) << 3);

        f32x4 acc[4][2];
        const f32x4 z = {0.f, 0.f, 0.f, 0.f};
#pragma unroll
        for (int i = 0; i < 4; ++i) { acc[i][0] = z; acc[i][1] = z; }

        float4 pa0 = *(const float4*)gA;
        float4 pa1 = *(const float4*)(gA + 4);
        f16x8 pbh0 = *(const f16x8*)gBh0, pbh1 = *(const f16x8*)gBh1;
        f16x8 pbl0 = *(const f16x8*)gBl0, pbl1 = *(const f16x8*)gBl1;

        for (int k0 = 0; k0 < 1024; k0 += 32) {
            __syncthreads();
            {
                const float av[8] = {pa0.x, pa0.y, pa0.z, pa0.w, pa1.x, pa1.y, pa1.z, pa1.w};
                f16x8 ah, al;
#pragma unroll
                for (int u = 0; u < 8; ++u) {
                    const f16 hi = (f16)av[u];
                    ah[u] = hi;
                    al[u] = (f16)(av[u] - (float)hi);
                }
                *(f16x8*)sAh = ah; *(f16x8*)sAl = al;
                *(f16x8*)sBh0 = pbh0; *(f16x8*)sBh1 = pbh1;
                *(f16x8*)sBl0 = pbl0; *(f16x8*)sBl1 = pbl1;
            }
            __syncthreads();
            if (k0 + 32 < 1024) {
                pa0 = *(const float4*)(gA + k0 + 32);
                pa1 = *(const float4*)(gA + k0 + 36);
                pbh0 = *(const f16x8*)(gBh0 + k0 + 32);
                pbh1 = *(const f16x8*)(gBh1 + k0 + 32);
                pbl0 = *(const f16x8*)(gBl0 + k0 + 32);
                pbl1 = *(const f16x8*)(gBl1 + k0 + 32);
            }
            f16x8 ah[4], al[4], bh[2], bl[2];
#pragma unroll
            for (int i = 0; i < 4; ++i) {
                ah[i] = *(const f16x8*)&Ash[(i * 16 + c) * 32 + foff];
                al[i] = *(const f16x8*)&Asl[(i * 16 + c) * 32 + foff];
            }
#pragma unroll
            for (int j = 0; j < 2; ++j) {
                bh[j] = *(const f16x8*)&Bsh[(w * 32 + j * 16 + c) * 32 + foff];
                bl[j] = *(const f16x8*)&Bsl[(w * 32 + j * 16 + c) * 32 + foff];
            }
#pragma unroll
            for (int i = 0; i < 4; ++i)
#pragma unroll
                for (int j = 0; j < 2; ++j) {
                    acc[i][j] = __builtin_amdgcn_mfma_f32_16x16x32_f16(ah[i], bh[j], acc[i][j], 0, 0, 0);
                    acc[i][j] = __builtin_amdgcn_mfma_f32_16x16x32_f16(ah[i], bl[j], acc[i][j], 0, 0, 0);
                    acc[i][j] = __builtin_amdgcn_mfma_f32_16x16x32_f16(al[i], bh[j], acc[i][j], 0, 0, 0);
                }
        }
        float b1v[2], w2v[2];
#pragma unroll
        for (int j = 0; j < 2; ++j) {
            const int col = w * 32 + j * 16 + c;
            b1v[j] = b1[col];
            w2v[j] = W2[col];
        }
        float part[4][4];
#pragma unroll
        for (int i = 0; i < 4; ++i)
#pragma unroll
            for (int r = 0; r < 4; ++r) {
                float s = 0.f;
#pragma unroll
                for (int j = 0; j < 2; ++j)
                    s += gelu_tanh(acc[i][j][r] + b1v[j]) * w2v[j];
                s += __shfl_xor(s, 1, 64);
                s += __shfl_xor(s, 2, 64);
                s += __shfl_xor(s, 4, 64);
                s += __shfl_xor(s, 8, 64);
                part[i][r] = s;
            }
        if (c == 0)
#pragma unroll
            for (int i = 0; i < 4; ++i)
#pragma unroll
                for (int r = 0; r < 4; ++r)
                    red[w][i * 16 + 4 * g + r] = part[i][r];
        __syncthreads();
        if (tid < 64)
            raw[m0 + tid] = red[0][tid] + red[1][tid] + red[2][tid] + red[3][tid] + b2[0];
        return;
    }

    // ---------------- gemm path (byte-identical math to gemm_gll) ---------
    {
        f16* As = sp.g.As; f16* Bs = sp.g.Bs;
        const int gid = bid - 64;
        const int m0 = (gid / 24) * 128, n0 = (gid % 24) * 128;
        const int wm = (w & 1) * 64, wn = (w >> 1) * 64;

        const int lrow = lane >> 3;            // 0..7
        const int lseg = (lane & 7) ^ lrow;    // XOR swizzle on global k-segment
        const f16* gA = A + (size_t)(m0 + w * 32 + lrow) * 1024 + lseg * 8;
        const f16* gB = Bt + (size_t)(n0 + w * 32 + lrow) * 1024 + lseg * 8;
        f16* lA = &As[(w * 32) * 64];
        f16* lB = &Bs[(w * 32) * 64];

        f32x4 acc[4][4];
        const f32x4 z = {0.f, 0.f, 0.f, 0.f};
#pragma unroll
        for (int i = 0; i < 4; ++i)
#pragma unroll
            for (int j = 0; j < 4; ++j) acc[i][j] = z;

        const int rsw = c & 7;
        for (int k0 = 0; k0 < 1024; k0 += 64) {
            __syncthreads();
#pragma unroll
            for (int p = 0; p < 4; ++p) {
                glds16(gA + (size_t)p * 8 * 1024 + k0, lA + p * 8 * 64);
                glds16(gB + (size_t)p * 8 * 1024 + k0, lB + p * 8 * 64);
            }
            __syncthreads();
#pragma unroll
            for (int s = 0; s < 2; ++s) {
                f16x8 af[4], bf[4];
#pragma unroll
                for (int i = 0; i < 4; ++i)
                    af[i] = *(const f16x8*)&As[(wm + i * 16 + c) * 64 + (((s * 4 + g) ^ rsw) * 8)];
#pragma unroll
                for (int j = 0; j < 4; ++j)
                    bf[j] = *(const f16x8*)&Bs[(wn + j * 16 + c) * 64 + (((s * 4 + g) ^ rsw) * 8)];
#pragma unroll
                for (int i = 0; i < 4; ++i)
#pragma unroll
                    for (int j = 0; j < 4; ++j)
                        acc[i][j] = __builtin_amdgcn_mfma_f32_16x16x32_f16(bf[j], af[i], acc[i][j], 0, 0, 0);
            }
        }
        // swapped D-layout: acc[i][j][r] = C[m0+wm+i*16+c][n0+wn+j*16+4g+r]
#pragma unroll
        for (int i = 0; i < 4; ++i)
#pragma unroll
            for (int j = 0; j < 4; ++j) {
                const size_t off = (size_t)(m0 + wm + i * 16 + c) * 3072 + n0 + wn + j * 16 + 4 * g;
                f16x4 v = {(f16)acc[i][j][0], (f16)acc[i][j][1],
                           (f16)acc[i][j][2], (f16)acc[i][j][3]};
                *(f16x4*)(Cb + off) = v;
            }
    }
}

// ---------------------------------------------------------------------------
// BM=64 GEMM for the OUT projection (f32 out): grid (8,64) = 512 = 2/CU.
// r9-proven operand-swap epilogue; r11-proven (total -11us).
// ---------------------------------------------------------------------------
__global__ __launch_bounds__(256, 4) void gemm_gll64(const f16* __restrict__ A,
                                                     const f16* __restrict__ Bt,
                                                     float* __restrict__ Cf,
                                                     int N) {
    __shared__ __align__(16) f16 As[64 * 64];   // 8 KB
    __shared__ __align__(16) f16 Bs[128 * 64];  // 16 KB
    const int tid = threadIdx.x;
    const int w = tid >> 6, lane = tid & 63;
    const int g = lane >> 4, c = lane & 15;
    const int m0 = blockIdx.y * 64, n0 = blockIdx.x * 128;
    const int wm = (w & 1) * 32, wn = (w >> 1) * 64;

    const int lrow = lane >> 3;            // 0..7
    const int lseg = (lane & 7) ^ lrow;    // XOR swizzle on global k-segment
    const f16* gA = A + (size_t)(m0 + w * 16 + lrow) * 1024 + lseg * 8;
    const f16* gB = Bt + (size_t)(n0 + w * 32 + lrow) * 1024 + lseg * 8;
    f16* lA = &As[(w * 16) * 64];
    f16* lB = &Bs[(w * 32) * 64];

    f32x4 acc[2][4];
    const f32x4 z = {0.f, 0.f, 0.f, 0.f};
#pragma unroll
    for (int i = 0; i < 2; ++i)
#pragma unroll
        for (int j = 0; j < 4; ++j) acc[i][j] = z;

    const int rsw = c & 7;
    for (int k0 = 0; k0 < 1024; k0 += 64) {
        __syncthreads();
#pragma unroll
        for (int p = 0; p < 2; ++p)
            glds16(gA + (size_t)p * 8 * 1024 + k0, lA + p * 8 * 64);
#pragma unroll
        for (int p = 0; p < 4; ++p)
            glds16(gB + (size_t)p * 8 * 1024 + k0, lB + p * 8 * 64);
        __syncthreads();
#pragma unroll
        for (int s = 0; s < 2; ++s) {
            f16x8 af[2], bf[4];
#pragma unroll
            for (int i = 0; i < 2; ++i)
                af[i] = *(const f16x8*)&As[(wm + i * 16 + c) * 64 + (((s * 4 + g) ^ rsw) * 8)];
#pragma unroll
            for (int j = 0; j < 4; ++j)
                bf[j] = *(const f16x8*)&Bs[(wn + j * 16 + c) * 64 + (((s * 4 + g) ^ rsw) * 8)];
#pragma unroll
            for (int i = 0; i < 2; ++i)
#pragma unroll
                for (int j = 0; j < 4; ++j)
                    acc[i][j] = __builtin_amdgcn_mfma_f32_16x16x32_f16(bf[j], af[i], acc[i][j], 0, 0, 0);
        }
    }
#pragma unroll
    for (int i = 0; i < 2; ++i)
#pragma unroll
        for (int j = 0; j < 4; ++j) {
            const size_t off = (size_t)(m0 + wm + i * 16 + c) * N + n0 + wn + j * 16 + 4 * g;
            *(f32x4*)(Cf + off) = acc[i][j];
        }
}

__device__ __forceinline__ double softplus_d(double x) {
    return (x > 0.0) ? x + log1p(exp(-x)) : log1p(exp(x));
}

__global__ __launch_bounds__(256) void repo_cumsum_kernel(const float* __restrict__ raw,
                                                          float* __restrict__ pos) {
    __shared__ double bufA[256];
    __shared__ double bufB[256];
    const int b = blockIdx.x;
    const int t = threadIdx.x;
    const float* r = raw + (size_t)b * SEQ;

    double loc[8];
    double sum = 0.0;
#pragma unroll
    for (int i = 0; i < 8; ++i) {
        sum += softplus_d((double)r[t * 8 + i]);
        loc[i] = sum;
    }
    bufA[t] = sum;
    __syncthreads();

    double* src = bufA;
    double* dst = bufB;
    for (int off = 1; off < 256; off <<= 1) {
        double v = src[t];
        if (t >= off) v += src[t - off];
        dst[t] = v;
        __syncthreads();
        double* tmp = src; src = dst; dst = tmp;
    }
    const double excl = src[t] - sum;
#pragma unroll
    for (int i = 0; i < 8; ++i)
        pos[(size_t)b * SEQ + t * 8 + i] = (float)(excl + loc[i]);
}

// ---------------------------------------------------------------------------
// cos/sin table [tok][32]
// ---------------------------------------------------------------------------
__global__ __launch_bounds__(256) void sctab_kernel(const float* __restrict__ pos,
                                                    float* __restrict__ costab,
                                                    float* __restrict__ sintab) {
    const int idx = blockIdx.x * 256 + threadIdx.x;
    const int tok = idx >> 5, i = idx & 31;
    const double ang = (double)pos[tok] * exp(-(double)i * 0.28782313662425574);
    double sa, ca;
    sincos(ang, &sa, &ca);
    costab[idx] = (float)ca;
    sintab[idx] = (float)sa;
}

// ---------------------------------------------------------------------------
// Pack K (rope fused) + V into fragment-major layouts; rope Q in-place.
// Proven r7/r2 layouts: K frag f16x8 at frag*512+lane*8; V frag f16x4 at
// frag*256+lane*4.
// ---------------------------------------------------------------------------
__global__ __launch_bounds__(256) void packkv_kernel(f16* __restrict__ qkv,
                                                     const float* __restrict__ costab,
                                                     const float* __restrict__ sintab,
                                                     f16* __restrict__ kfo,
                                                     f16* __restrict__ vfo) {
    __shared__ __align__(16) f16 kds[64][72];
    __shared__ __align__(16) f16 vds[64][72];
    const int t = threadIdx.x;
    const int s0 = blockIdx.x * 64;
    const int h = blockIdx.y, b = blockIdx.z;
    const int key = t >> 2, part = t & 3;
    const int tok = b * SEQ + s0 + key;
    {
        float cs[8], sn[8];
        *(float4*)cs       = *(const float4*)(costab + tok * 32 + part * 8);
        *(float4*)(cs + 4) = *(const float4*)(costab + tok * 32 + part * 8 + 4);
        *(float4*)sn       = *(const float4*)(sintab + tok * 32 + part * 8);
        *(float4*)(sn + 4) = *(const float4*)(sintab + tok * 32 + part * 8 + 4);
        f16* qrow = qkv + (size_t)tok * 3072 + h * HEAD_DIM;
        {
            f16x8 lo = *(const f16x8*)(qrow + part * 8);
            f16x8 hi = *(const f16x8*)(qrow + part * 8 + 32);
#pragma unroll
            for (int u = 0; u < 8; ++u) {
                const float l = (float)lo[u], hh = (float)hi[u];
                lo[u] = (f16)(l * cs[u] - hh * sn[u]);
                hi[u] = (f16)(l * sn[u] + hh * cs[u]);
            }
            *(f16x8*)(qrow + part * 8) = lo;
            *(f16x8*)(qrow + part * 8 + 32) = hi;
        }
        const f16* krow = qrow + 1024;
        {
            f16x8 lo = *(const f16x8*)(krow + part * 8);
            f16x8 hi = *(const f16x8*)(krow + part * 8 + 32);
#pragma unroll
            for (int u = 0; u < 8; ++u) {
                const float l = (float)lo[u], hh = (float)hi[u];
                kds[key][part * 8 + u]      = (f16)(l * cs[u] - hh * sn[u]);
                kds[key][32 + part * 8 + u] = (f16)(l * sn[u] + hh * cs[u]);
            }
        }
        const f16* vrow = qrow + 2048;
        f16x8 v0 = *(const f16x8*)(vrow + part * 16);
        f16x8 v1 = *(const f16x8*)(vrow + part * 16 + 8);
#pragma unroll
        for (int u = 0; u < 8; ++u) {
            vds[part * 16 + u][key] = v0[u];
            vds[part * 16 + 8 + u][key] = v1[u];
        }
    }
    __syncthreads();
    const size_t cb = ((size_t)((b * HEADS + h) * 32) + blockIdx.x) * 4096;
#pragma unroll
    for (int p = 0; p < 2; ++p) {
        const int idx = p * 256 + t;
        const int frag = idx >> 6, lane = idx & 63;
        const int jn = frag >> 1, half = frag & 1, g = lane >> 4, c = lane & 15;
        *(f16x8*)(kfo + cb + frag * 512 + lane * 8) =
            *(const f16x8*)(&kds[jn * 16 + c][half * 32 + g * 8]);
    }
#pragma unroll
    for (int p = 0; p < 4; ++p) {
        const int idx = p * 256 + t;
        const int frag = idx >> 6, lane = idx & 63;
        const int jd = frag >> 2, jn = frag & 3, g = lane >> 4, c = lane & 15;
        *(f16x4*)(vfo + cb + frag * 256 + lane * 4) =
            *(const f16x4*)(&vds[jd * 16 + c][jn * 16 + 4 * g]);
    }
}

// ---------------------------------------------------------------------------
// MFMA flash attention, no split-K (r7/r9 structure) with T14 reg-staging
// (r10). attn line is CLOSED: r1/r3/r4/r5/r8/r10 all confirmed this loop as
// the local optimum (~54us).
// ---------------------------------------------------------------------------
__global__ __launch_bounds__(256, 2) void attn_f16(const f16* __restrict__ qkv,
                                                   const f16* __restrict__ kfr,
                                                   const f16* __restrict__ vfr,
                                                   f16* __restrict__ aof0) {
    __shared__ __align__(16) f16 kls[4096];     // one K chunk (8 KB)
    __shared__ __align__(16) f16 vls[4096];     // one V chunk (8 KB)
    __shared__ __align__(16) f16 ot[4][32][72]; // epilogue transpose (18 KB)
    const int tid = threadIdx.x;
    const int w = tid >> 6, lane = tid & 63;
    const int g = lane >> 4, c = lane & 15;

    // XCD-aware decode: wid -> (xcd, slot) -> (combo=(h,b), xblk)
    const int wid = blockIdx.x;                 // 0..511
    const int xcd = wid & 7, slot = wid >> 3;   // slot 0..63
    const int combo = xcd * 4 + (slot >> 4);    // 0..31: 4 (h,b) combos/XCD
    const int xblk = slot & 15;                 // 0..15
    const int h = combo & 15;
    const int b = combo >> 4;

    const int bh = b * HEADS + h;
    const int row0 = xblk * 128 + w * 32;

    const f16* qb = qkv + (size_t)(b * SEQ + row0) * 3072 + h * HEAD_DIM + g * 8;
    // per-thread staging addresses (wave w owns bytes [w*2KB, w*2KB+2KB))
    const f16* kfb = kfr + (size_t)bh * 32 * 4096 + w * 1024 + lane * 8;
    const f16* vfb = vfr + (size_t)bh * 32 * 4096 + w * 1024 + lane * 8;
    f16* kd = kls + w * 1024 + lane * 8;
    f16* vd = vls + w * 1024 + lane * 8;

    f16x8 qf[2][2];
#pragma unroll
    for (int i = 0; i < 2; ++i) {
        qf[i][0] = *(const f16x8*)(qb + (size_t)(i * 16 + c) * 3072);
        qf[i][1] = *(const f16x8*)(qb + (size_t)(i * 16 + c) * 3072 + 32);
    }
    const f32x4 z = {0.f, 0.f, 0.f, 0.f};
    f32x4 acc[4][2];
#pragma unroll
    for (int jd = 0; jd < 4; ++jd) { acc[jd][0] = z; acc[jd][1] = z; }
    float dloc[2] = {0.f, 0.f};   // denominator partials (VALU pipe)

    const float SC = 0.125f * 1.4426950408889634f;

    // prologue: chunk 0 -> regs
    f16x8 kr0 = *(const f16x8*)(kfb);
    f16x8 kr1 = *(const f16x8*)(kfb + 512);
    f16x8 vr0 = *(const f16x8*)(vfb);
    f16x8 vr1 = *(const f16x8*)(vfb + 512);

    for (int cc = 0; cc < 32; ++cc) {
        __syncthreads();   // prior chunk's ds_reads done; staging regs landed
        *(f16x8*)kd         = kr0;
        *(f16x8*)(kd + 512) = kr1;
        *(f16x8*)vd         = vr0;
        *(f16x8*)(vd + 512) = vr1;
        __syncthreads();   // ds_writes visible block-wide
        if (cc + 1 < 32) {
            // issue next chunk's loads AFTER the barrier: they stay in flight
            // across the whole compute phase (no exposed latency)
            const f16* kg = kfb + (size_t)(cc + 1) * 4096;
            const f16* vg = vfb + (size_t)(cc + 1) * 4096;
            kr0 = *(const f16x8*)(kg);
            kr1 = *(const f16x8*)(kg + 512);
            vr0 = *(const f16x8*)(vg);
            vr1 = *(const f16x8*)(vg + 512);
        }

        f16x8 kf[8];
        f16x4 vf[16];
#pragma unroll
        for (int f = 0; f < 8; ++f) kf[f] = *(const f16x8*)(kls + lane * 8 + f * 512);
#pragma unroll
        for (int f = 0; f < 16; ++f) vf[f] = *(const f16x4*)(vls + lane * 4 + f * 256);

#pragma unroll
        for (int i = 0; i < 2; ++i) {
            f32x4 s[4];
#pragma unroll
            for (int jn = 0; jn < 4; ++jn) {
                s[jn] = __builtin_amdgcn_mfma_f32_16x16x32_f16(kf[jn * 2], qf[i][0], z, 0, 0, 0);
                s[jn] = __builtin_amdgcn_mfma_f32_16x16x32_f16(kf[jn * 2 + 1], qf[i][1], s[jn], 0, 0, 0);
            }
#pragma unroll
            for (int jn = 0; jn < 4; ++jn) {
                const float e0 = __builtin_amdgcn_exp2f(fmaf(s[jn][0], SC, -8.0f));
                const float e1 = __builtin_amdgcn_exp2f(fmaf(s[jn][1], SC, -8.0f));
                const float e2 = __builtin_amdgcn_exp2f(fmaf(s[jn][2], SC, -8.0f));
                const float e3 = __builtin_amdgcn_exp2f(fmaf(s[jn][3], SC, -8.0f));
                dloc[i] += (e0 + e1) + (e2 + e3);
                f16x4 pf = {(f16)e0, (f16)e1, (f16)e2, (f16)e3};
#pragma unroll
                for (int jd = 0; jd < 4; ++jd)
                    acc[jd][i] = __builtin_amdgcn_mfma_f32_16x16x16f16(vf[jd * 4 + jn], pf, acc[jd][i], 0, 0, 0);
            }
        }
    }

    // denominators: reduce across the 4 g-groups (lanes c, 16+c, 32+c, 48+c);
    // after the two xors every lane holds the full sum for its query (i, c).
    float inv[2];
#pragma unroll
    for (int i = 0; i < 2; ++i) {
        dloc[i] += __shfl_xor(dloc[i], 16, 64);
        dloc[i] += __shfl_xor(dloc[i], 32, 64);
        inv[i] = 1.0f / dloc[i];   // 2^-8 bias cancels between num and denom
    }

    // numerator: normalize in f32, O^T regs -> wave-private LDS transpose ->
    // coalesced f16 store (single output, no combine pass)
    __syncthreads();   // all ds_reads of the last chunk done before ot reuse
#pragma unroll
    for (int i = 0; i < 2; ++i)
#pragma unroll
        for (int jd = 0; jd < 4; ++jd)
#pragma unroll
            for (int r = 0; r < 4; ++r)
                ot[w][i * 16 + c][jd * 16 + 4 * g + r] = (f16)(acc[jd][i][r] * inv[i]);
    const int tr = lane >> 1, hf = lane & 1;
    f16* aob = aof0 + (size_t)(b * SEQ + row0 + tr) * HIDDEN + h * HEAD_DIM + hf * 32;
#pragma unroll
    for (int q = 0; q < 4; ++q)
        *(f16x8*)(aob + q * 8) = *(const f16x8*)(&ot[w][tr][hf * 32 + q * 8]);
}

// ---------------------------------------------------------------------------
// launch
// ---------------------------------------------------------------------------
extern "C" void kernel_launch(void* const* d_in, const int* in_sizes, int n_in,
                              void* d_out, int out_size, void* d_ws, size_t ws_size,
                              hipStream_t stream) {
    const float* x   = (const float*)d_in[0];
    const float* W_q = (const float*)d_in[1];
    const float* W_k = (const float*)d_in[2];
    const float* W_v = (const float*)d_in[3];
    const float* W_o = (const float*)d_in[4];
    const float* rW1 = (const float*)d_in[5];
    const float* rb1 = (const float*)d_in[6];
    const float* rW2 = (const float*)d_in[7];
    const float* rb2 = (const float*)d_in[8];
    float* out = (float*)d_out;

    const size_t MAT = (size_t)TOKENS * HIDDEN;   // 4M
    const size_t WSZ = (size_t)HIDDEN * HIDDEN;   // 1M
    f16* x16  = (f16*)d_ws;
    f16* wqkv = x16 + MAT;            // [3072][1024]; wot contiguous after
    f16* wot  = wqkv + 3 * WSZ;
    f16* qkv  = wot + WSZ;            // [4096][3072]
    f16* kfr  = qkv + 3 * MAT;
    f16* vfr  = kfr + MAT;
    f16* aof0 = vfr + MAT;
    f16* aof1 = aof0 + MAT;           // unused (no split-K)
    f16* w1h  = aof1 + MAT;           // [128][1024]
    f16* w1l  = w1h + POS_DIM * HIDDEN;
    float* raw    = (float*)(w1l + POS_DIM * HIDDEN);
    float* pos    = raw + TOKENS;
    float* costab = pos + TOKENS;
    float* sintab = costab + TOKENS * 32;

    // merged preprocessing: cast_x (2048) + cast_wt4 (4096) + cast_w1t (128)
    cast_all_kernel<<<6272, 256, 0, stream>>>(x, W_q, W_k, W_v, W_o, rW1,
                                              x16, wqkv, w1h, w1l);

    // fused qkv GEMM + repo MLP: repo blocks [0,64) dispatched first, gemm
    // blocks [64, 832) fill the machine -> repo's serial slot disappears
    gemm_repo_kernel<<<832, 256, 0, stream>>>(x16, wqkv, qkv,
                                              x, w1h, w1l, rb1, rW2, rb2, raw);

    repo_cumsum_kernel<<<BATCH, 256, 0, stream>>>(raw, pos);
    sctab_kernel<<<TOKENS * 32 / 256, 256, 0, stream>>>(pos, costab, sintab);

    packkv_kernel<<<dim3(SEQ / 64, HEADS, BATCH), 256, 0, stream>>>(qkv, costab, sintab, kfr, vfr);

    attn_f16<<<dim3(512), 256, 0, stream>>>(qkv, kfr, vfr, aof0);

    gemm_gll64<<<dim3(8, 64), 256, 0, stream>>>(aof0, wot, out, 1024);
}

// Round 13
// 217.995 us; speedup vs baseline: 1.1744x; 1.0064x over previous
//
#include <hip/hip_runtime.h>
#include <hip/hip_bf16.h>
#include <math.h>

#define HIDDEN 1024
#define HEADS 16
#define HEAD_DIM 64
#define POS_DIM 128
#define BATCH 2
#define SEQ 2048
#define TOKENS (BATCH * SEQ)

typedef _Float16 f16;
typedef __attribute__((ext_vector_type(8))) _Float16 f16x8;
typedef __attribute__((ext_vector_type(4))) _Float16 f16x4;
typedef __attribute__((ext_vector_type(4))) float f32x4;

// async global->LDS, 16B per lane; LDS dest = wave-uniform base + lane*16
__device__ __forceinline__ void glds16(const f16* g, f16* l) {
    __builtin_amdgcn_global_load_lds((const __attribute__((address_space(1))) unsigned int*)g,
                                     (__attribute__((address_space(3))) unsigned int*)l, 16, 0, 0);
}

// ---------------------------------------------------------------------------
// MERGED preprocessing (1 launch): block-uniform dispatch on bid.
//   [0, 2048)        : cast x fp32->f16, 8 elems/thread
//   [2048, 6144)     : 4 weights [1024][1024] -> Wt f16 transposed
//   [6144, 6272)     : W1 [1024][128] -> w1t hi/lo split transposed
// ---------------------------------------------------------------------------
__global__ __launch_bounds__(256) void cast_all_kernel(const float* __restrict__ x,
                                                       const float* __restrict__ W0,
                                                       const float* __restrict__ W1,
                                                       const float* __restrict__ W2,
                                                       const float* __restrict__ W3,
                                                       const float* __restrict__ rW1,
                                                       f16* __restrict__ x16,
                                                       f16* __restrict__ Wt,
                                                       f16* __restrict__ Wh,
                                                       f16* __restrict__ Wl) {
    __shared__ float ts[32][33];
    const int bid = blockIdx.x;
    const int t = threadIdx.x;
    if (bid < 2048) {
        const int i = (bid * 256 + t) * 8;
        const float4 u = *(const float4*)(x + i);
        const float4 v = *(const float4*)(x + i + 4);
        f16x8 r = {(f16)u.x, (f16)u.y, (f16)u.z, (f16)u.w,
                   (f16)v.x, (f16)v.y, (f16)v.z, (f16)v.w};
        *(f16x8*)(x16 + i) = r;
        return;
    }
    if (bid < 6144) {
        const int local = bid - 2048;
        const int z = local >> 10;
        const int by = (local & 1023) >> 5, bx = local & 31;
        const float* W = (z == 0) ? W0 : (z == 1) ? W1 : (z == 2) ? W2 : W3;
        f16* dst = Wt + (size_t)z * HIDDEN * HIDDEN;
        const int k0 = by * 32, n0 = bx * 32;
        {
            const int r = t >> 3, c4 = (t & 7) * 4;
            const float4 u = *(const float4*)(W + (size_t)(k0 + r) * HIDDEN + n0 + c4);
            ts[r][c4 + 0] = u.x; ts[r][c4 + 1] = u.y; ts[r][c4 + 2] = u.z; ts[r][c4 + 3] = u.w;
        }
        __syncthreads();
        {
            const int r = t >> 3, c4 = (t & 7) * 4;
            f16* o = dst + (size_t)(n0 + r) * HIDDEN + k0 + c4;
            o[0] = (f16)ts[c4 + 0][r]; o[1] = (f16)ts[c4 + 1][r];
            o[2] = (f16)ts[c4 + 2][r]; o[3] = (f16)ts[c4 + 3][r];
        }
        return;
    }
    {
        const int local = bid - 6144;          // [0,128): y=local>>2 in [0,32), x=local&3
        const int k0 = (local >> 2) * 32, p0 = (local & 3) * 32;
        {
            const int r = t >> 3, c4 = (t & 7) * 4;
            const float4 u = *(const float4*)(rW1 + (size_t)(k0 + r) * POS_DIM + p0 + c4);
            ts[r][c4 + 0] = u.x; ts[r][c4 + 1] = u.y; ts[r][c4 + 2] = u.z; ts[r][c4 + 3] = u.w;
        }
        __syncthreads();
        {
            const int r = t >> 3, c4 = (t & 7) * 4;
            f16* oh = Wh + (size_t)(p0 + r) * HIDDEN + k0 + c4;
            f16* ol = Wl + (size_t)(p0 + r) * HIDDEN + k0 + c4;
#pragma unroll
            for (int u = 0; u < 4; ++u) {
                const float v = ts[c4 + u][r];
                const f16 hi = (f16)v;
                oh[u] = hi;
                ol[u] = (f16)(v - (float)hi);
            }
        }
    }
}

__device__ __forceinline__ float gelu_tanh(float x) {
    const float kA = 0.7978845608028654f;
    return 0.5f * x * (1.0f + tanhf(kA * (x + 0.044715f * x * x * x)));
}

// ---------------------------------------------------------------------------
// FUSED qkv-GEMM + RePo-MLP (r12-proven, total -20us). NEW this round: gemm
// path BM 128->64 (r11's proven transformation): 768 -> 1536 gemm blocks,
// ~5-6 blocks/CU resident (LDS union 25.6KB, VGPR ~90) -- the 2-barrier
// drain per K-step gets real TLP cover. Per-element K-chains unchanged ->
// bitwise-identical C. bid<64 -> repo path (dispatched first); bid>=64 ->
// gemm path: gid=bid-64, m0=(gid/24)*64, n0=(gid%24)*128. B-panels are
// XCD-local by construction (24 = 0 mod 8 -> all sharers of an n-panel land
// on XCD n%8).
// ---------------------------------------------------------------------------
union SmemPool {
    struct { f16 As[64 * 64]; f16 Bs[128 * 64]; } g;                     // 24 KB
    struct { f16 Ash[64 * 32]; f16 Asl[64 * 32];
             f16 Bsh[128 * 32]; f16 Bsl[128 * 32]; float red[4][64]; } r; // 25 KB
};

__global__ __launch_bounds__(256, 2) void gemm_repo_kernel(
        const f16* __restrict__ A, const f16* __restrict__ Bt, f16* __restrict__ Cb,
        const float* __restrict__ x,
        const f16* __restrict__ w1h, const f16* __restrict__ w1l,
        const float* __restrict__ b1, const float* __restrict__ W2,
        const float* __restrict__ b2, float* __restrict__ raw) {
    __shared__ __align__(16) SmemPool sp;
    const int bid = blockIdx.x;
    const int tid = threadIdx.x;
    const int w = tid >> 6, lane = tid & 63;
    const int g = lane >> 4, c = lane & 15;

    if (bid < 64) {
        // ---------------- repo path (byte-identical math to repo_mfma) ----
        f16* Ash = sp.r.Ash; f16* Asl = sp.r.Asl;
        f16* Bsh = sp.r.Bsh; f16* Bsl = sp.r.Bsl;
        float (*red)[64] = sp.r.red;
        const int m0 = bid * 64;

        const int arow = tid >> 2, aseg = tid & 3;
        const int aslot = (aseg ^ ((arow ^ (arow >> 2)) & 3)) << 3;
        const float* gA = x + (size_t)(m0 + arow) * 1024 + aseg * 8;
        const f16* gBh0 = w1h + (size_t)arow * 1024 + aseg * 8;
        const f16* gBh1 = w1h + (size_t)(arow + 64) * 1024 + aseg * 8;
        const f16* gBl0 = w1l + (size_t)arow * 1024 + aseg * 8;
        const f16* gBl1 = w1l + (size_t)(arow + 64) * 1024 + aseg * 8;
        f16* sAh = &Ash[arow * 32 + aslot];
        f16* sAl = &Asl[arow * 32 + aslot];
        f16* sBh0 = &Bsh[arow * 32 + aslot];
        f16* sBh1 = &Bsh[(arow + 64) * 32 + aslot];
        f16* sBl0 = &Bsl[arow * 32 + aslot];
        f16* sBl1 = &Bsl[(arow + 64) * 32 + aslot];

        const int foff = ((g ^ ((c ^ (c >> 2)) & 3)) << 3);

        f32x4 acc[4][2];
        const f32x4 z = {0.f, 0.f, 0.f, 0.f};
#pragma unroll
        for (int i = 0; i < 4; ++i) { acc[i][0] = z; acc[i][1] = z; }

        float4 pa0 = *(const float4*)gA;
        float4 pa1 = *(const float4*)(gA + 4);
        f16x8 pbh0 = *(const f16x8*)gBh0, pbh1 = *(const f16x8*)gBh1;
        f16x8 pbl0 = *(const f16x8*)gBl0, pbl1 = *(const f16x8*)gBl1;

        for (int k0 = 0; k0 < 1024; k0 += 32) {
            __syncthreads();
            {
                const float av[8] = {pa0.x, pa0.y, pa0.z, pa0.w, pa1.x, pa1.y, pa1.z, pa1.w};
                f16x8 ah, al;
#pragma unroll
                for (int u = 0; u < 8; ++u) {
                    const f16 hi = (f16)av[u];
                    ah[u] = hi;
                    al[u] = (f16)(av[u] - (float)hi);
                }
                *(f16x8*)sAh = ah; *(f16x8*)sAl = al;
                *(f16x8*)sBh0 = pbh0; *(f16x8*)sBh1 = pbh1;
                *(f16x8*)sBl0 = pbl0; *(f16x8*)sBl1 = pbl1;
            }
            __syncthreads();
            if (k0 + 32 < 1024) {
                pa0 = *(const float4*)(gA + k0 + 32);
                pa1 = *(const float4*)(gA + k0 + 36);
                pbh0 = *(const f16x8*)(gBh0 + k0 + 32);
                pbh1 = *(const f16x8*)(gBh1 + k0 + 32);
                pbl0 = *(const f16x8*)(gBl0 + k0 + 32);
                pbl1 = *(const f16x8*)(gBl1 + k0 + 32);
            }
            f16x8 ah[4], al[4], bh[2], bl[2];
#pragma unroll
            for (int i = 0; i < 4; ++i) {
                ah[i] = *(const f16x8*)&Ash[(i * 16 + c) * 32 + foff];
                al[i] = *(const f16x8*)&Asl[(i * 16 + c) * 32 + foff];
            }
#pragma unroll
            for (int j = 0; j < 2; ++j) {
                bh[j] = *(const f16x8*)&Bsh[(w * 32 + j * 16 + c) * 32 + foff];
                bl[j] = *(const f16x8*)&Bsl[(w * 32 + j * 16 + c) * 32 + foff];
            }
#pragma unroll
            for (int i = 0; i < 4; ++i)
#pragma unroll
                for (int j = 0; j < 2; ++j) {
                    acc[i][j] = __builtin_amdgcn_mfma_f32_16x16x32_f16(ah[i], bh[j], acc[i][j], 0, 0, 0);
                    acc[i][j] = __builtin_amdgcn_mfma_f32_16x16x32_f16(ah[i], bl[j], acc[i][j], 0, 0, 0);
                    acc[i][j] = __builtin_amdgcn_mfma_f32_16x16x32_f16(al[i], bh[j], acc[i][j], 0, 0, 0);
                }
        }
        float b1v[2], w2v[2];
#pragma unroll
        for (int j = 0; j < 2; ++j) {
            const int col = w * 32 + j * 16 + c;
            b1v[j] = b1[col];
            w2v[j] = W2[col];
        }
        float part[4][4];
#pragma unroll
        for (int i = 0; i < 4; ++i)
#pragma unroll
            for (int r = 0; r < 4; ++r) {
                float s = 0.f;
#pragma unroll
                for (int j = 0; j < 2; ++j)
                    s += gelu_tanh(acc[i][j][r] + b1v[j]) * w2v[j];
                s += __shfl_xor(s, 1, 64);
                s += __shfl_xor(s, 2, 64);
                s += __shfl_xor(s, 4, 64);
                s += __shfl_xor(s, 8, 64);
                part[i][r] = s;
            }
        if (c == 0)
#pragma unroll
            for (int i = 0; i < 4; ++i)
#pragma unroll
                for (int r = 0; r < 4; ++r)
                    red[w][i * 16 + 4 * g + r] = part[i][r];
        __syncthreads();
        if (tid < 64)
            raw[m0 + tid] = red[0][tid] + red[1][tid] + red[2][tid] + red[3][tid] + b2[0];
        return;
    }

    // ---------------- gemm path: BM=64 x BN=128 tiles ---------------------
    {
        f16* As = sp.g.As; f16* Bs = sp.g.Bs;
        const int gid = bid - 64;
        const int m0 = (gid / 24) * 64, n0 = (gid % 24) * 128;
        const int wm = (w & 1) * 32, wn = (w >> 1) * 64;

        const int lrow = lane >> 3;            // 0..7
        const int lseg = (lane & 7) ^ lrow;    // XOR swizzle on global k-segment
        const f16* gA = A + (size_t)(m0 + w * 16 + lrow) * 1024 + lseg * 8;
        const f16* gB = Bt + (size_t)(n0 + w * 32 + lrow) * 1024 + lseg * 8;
        f16* lA = &As[(w * 16) * 64];
        f16* lB = &Bs[(w * 32) * 64];

        f32x4 acc[2][4];
        const f32x4 z = {0.f, 0.f, 0.f, 0.f};
#pragma unroll
        for (int i = 0; i < 2; ++i)
#pragma unroll
            for (int j = 0; j < 4; ++j) acc[i][j] = z;

        const int rsw = c & 7;
        for (int k0 = 0; k0 < 1024; k0 += 64) {
            __syncthreads();
#pragma unroll
            for (int p = 0; p < 2; ++p)
                glds16(gA + (size_t)p * 8 * 1024 + k0, lA + p * 8 * 64);
#pragma unroll
            for (int p = 0; p < 4; ++p)
                glds16(gB + (size_t)p * 8 * 1024 + k0, lB + p * 8 * 64);
            __syncthreads();
#pragma unroll
            for (int s = 0; s < 2; ++s) {
                f16x8 af[2], bf[4];
#pragma unroll
                for (int i = 0; i < 2; ++i)
                    af[i] = *(const f16x8*)&As[(wm + i * 16 + c) * 64 + (((s * 4 + g) ^ rsw) * 8)];
#pragma unroll
                for (int j = 0; j < 4; ++j)
                    bf[j] = *(const f16x8*)&Bs[(wn + j * 16 + c) * 64 + (((s * 4 + g) ^ rsw) * 8)];
#pragma unroll
                for (int i = 0; i < 2; ++i)
#pragma unroll
                    for (int j = 0; j < 4; ++j)
                        acc[i][j] = __builtin_amdgcn_mfma_f32_16x16x32_f16(bf[j], af[i], acc[i][j], 0, 0, 0);
            }
        }
        // swapped D-layout: acc[i][j][r] = C[m0+wm+i*16+c][n0+wn+j*16+4g+r]
#pragma unroll
        for (int i = 0; i < 2; ++i)
#pragma unroll
            for (int j = 0; j < 4; ++j) {
                const size_t off = (size_t)(m0 + wm + i * 16 + c) * 3072 + n0 + wn + j * 16 + 4 * g;
                f16x4 v = {(f16)acc[i][j][0], (f16)acc[i][j][1],
                           (f16)acc[i][j][2], (f16)acc[i][j][3]};
                *(f16x4*)(Cb + off) = v;
            }
    }
}

// ---------------------------------------------------------------------------
// OUT projection GEMM: BM=64 x BN=64 tiles -> grid (16,64) = 1024 blocks =
// 4/CU (was 2/CU at BN=128; r11 proved the 1->2 step, this is the same
// transformation again). LDS 16 KB. Per-element K-chains unchanged ->
// bitwise-identical C.
// ---------------------------------------------------------------------------
__global__ __launch_bounds__(256, 4) void gemm_gll64(const f16* __restrict__ A,
                                                     const f16* __restrict__ Bt,
                                                     float* __restrict__ Cf,
                                                     int N) {
    __shared__ __align__(16) f16 As[64 * 64];   // 8 KB
    __shared__ __align__(16) f16 Bs[64 * 64];   // 8 KB
    const int tid = threadIdx.x;
    const int w = tid >> 6, lane = tid & 63;
    const int g = lane >> 4, c = lane & 15;
    const int m0 = blockIdx.y * 64, n0 = blockIdx.x * 64;
    const int wm = (w & 1) * 32, wn = (w >> 1) * 32;

    const int lrow = lane >> 3;            // 0..7
    const int lseg = (lane & 7) ^ lrow;    // XOR swizzle on global k-segment
    const f16* gA = A + (size_t)(m0 + w * 16 + lrow) * 1024 + lseg * 8;
    const f16* gB = Bt + (size_t)(n0 + w * 16 + lrow) * 1024 + lseg * 8;
    f16* lA = &As[(w * 16) * 64];
    f16* lB = &Bs[(w * 16) * 64];

    f32x4 acc[2][2];
    const f32x4 z = {0.f, 0.f, 0.f, 0.f};
#pragma unroll
    for (int i = 0; i < 2; ++i)
#pragma unroll
        for (int j = 0; j < 2; ++j) acc[i][j] = z;

    const int rsw = c & 7;
    for (int k0 = 0; k0 < 1024; k0 += 64) {
        __syncthreads();
#pragma unroll
        for (int p = 0; p < 2; ++p) {
            glds16(gA + (size_t)p * 8 * 1024 + k0, lA + p * 8 * 64);
            glds16(gB + (size_t)p * 8 * 1024 + k0, lB + p * 8 * 64);
        }
        __syncthreads();
#pragma unroll
        for (int s = 0; s < 2; ++s) {
            f16x8 af[2], bf[2];
#pragma unroll
            for (int i = 0; i < 2; ++i)
                af[i] = *(const f16x8*)&As[(wm + i * 16 + c) * 64 + (((s * 4 + g) ^ rsw) * 8)];
#pragma unroll
            for (int j = 0; j < 2; ++j)
                bf[j] = *(const f16x8*)&Bs[(wn + j * 16 + c) * 64 + (((s * 4 + g) ^ rsw) * 8)];
#pragma unroll
            for (int i = 0; i < 2; ++i)
#pragma unroll
                for (int j = 0; j < 2; ++j)
                    acc[i][j] = __builtin_amdgcn_mfma_f32_16x16x32_f16(bf[j], af[i], acc[i][j], 0, 0, 0);
        }
    }
#pragma unroll
    for (int i = 0; i < 2; ++i)
#pragma unroll
        for (int j = 0; j < 2; ++j) {
            const size_t off = (size_t)(m0 + wm + i * 16 + c) * N + n0 + wn + j * 16 + 4 * g;
            *(f32x4*)(Cf + off) = acc[i][j];
        }
}

__device__ __forceinline__ double softplus_d(double x) {
    return (x > 0.0) ? x + log1p(exp(-x)) : log1p(exp(x));
}

__global__ __launch_bounds__(256) void repo_cumsum_kernel(const float* __restrict__ raw,
                                                          float* __restrict__ pos) {
    __shared__ double bufA[256];
    __shared__ double bufB[256];
    const int b = blockIdx.x;
    const int t = threadIdx.x;
    const float* r = raw + (size_t)b * SEQ;

    double loc[8];
    double sum = 0.0;
#pragma unroll
    for (int i = 0; i < 8; ++i) {
        sum += softplus_d((double)r[t * 8 + i]);
        loc[i] = sum;
    }
    bufA[t] = sum;
    __syncthreads();

    double* src = bufA;
    double* dst = bufB;
    for (int off = 1; off < 256; off <<= 1) {
        double v = src[t];
        if (t >= off) v += src[t - off];
        dst[t] = v;
        __syncthreads();
        double* tmp = src; src = dst; dst = tmp;
    }
    const double excl = src[t] - sum;
#pragma unroll
    for (int i = 0; i < 8; ++i)
        pos[(size_t)b * SEQ + t * 8 + i] = (float)(excl + loc[i]);
}

// ---------------------------------------------------------------------------
// cos/sin table [tok][32]
// ---------------------------------------------------------------------------
__global__ __launch_bounds__(256) void sctab_kernel(const float* __restrict__ pos,
                                                    float* __restrict__ costab,
                                                    float* __restrict__ sintab) {
    const int idx = blockIdx.x * 256 + threadIdx.x;
    const int tok = idx >> 5, i = idx & 31;
    const double ang = (double)pos[tok] * exp(-(double)i * 0.28782313662425574);
    double sa, ca;
    sincos(ang, &sa, &ca);
    costab[idx] = (float)ca;
    sintab[idx] = (float)sa;
}

// ---------------------------------------------------------------------------
// Pack K (rope fused) + V into fragment-major layouts; rope Q in-place.
// Proven r7/r2 layouts: K frag f16x8 at frag*512+lane*8; V frag f16x4 at
// frag*256+lane*4.
// ---------------------------------------------------------------------------
__global__ __launch_bounds__(256) void packkv_kernel(f16* __restrict__ qkv,
                                                     const float* __restrict__ costab,
                                                     const float* __restrict__ sintab,
                                                     f16* __restrict__ kfo,
                                                     f16* __restrict__ vfo) {
    __shared__ __align__(16) f16 kds[64][72];
    __shared__ __align__(16) f16 vds[64][72];
    const int t = threadIdx.x;
    const int s0 = blockIdx.x * 64;
    const int h = blockIdx.y, b = blockIdx.z;
    const int key = t >> 2, part = t & 3;
    const int tok = b * SEQ + s0 + key;
    {
        float cs[8], sn[8];
        *(float4*)cs       = *(const float4*)(costab + tok * 32 + part * 8);
        *(float4*)(cs + 4) = *(const float4*)(costab + tok * 32 + part * 8 + 4);
        *(float4*)sn       = *(const float4*)(sintab + tok * 32 + part * 8);
        *(float4*)(sn + 4) = *(const float4*)(sintab + tok * 32 + part * 8 + 4);
        f16* qrow = qkv + (size_t)tok * 3072 + h * HEAD_DIM;
        {
            f16x8 lo = *(const f16x8*)(qrow + part * 8);
            f16x8 hi = *(const f16x8*)(qrow + part * 8 + 32);
#pragma unroll
            for (int u = 0; u < 8; ++u) {
                const float l = (float)lo[u], hh = (float)hi[u];
                lo[u] = (f16)(l * cs[u] - hh * sn[u]);
                hi[u] = (f16)(l * sn[u] + hh * cs[u]);
            }
            *(f16x8*)(qrow + part * 8) = lo;
            *(f16x8*)(qrow + part * 8 + 32) = hi;
        }
        const f16* krow = qrow + 1024;
        {
            f16x8 lo = *(const f16x8*)(krow + part * 8);
            f16x8 hi = *(const f16x8*)(krow + part * 8 + 32);
#pragma unroll
            for (int u = 0; u < 8; ++u) {
                const float l = (float)lo[u], hh = (float)hi[u];
                kds[key][part * 8 + u]      = (f16)(l * cs[u] - hh * sn[u]);
                kds[key][32 + part * 8 + u] = (f16)(l * sn[u] + hh * cs[u]);
            }
        }
        const f16* vrow = qrow + 2048;
        f16x8 v0 = *(const f16x8*)(vrow + part * 16);
        f16x8 v1 = *(const f16x8*)(vrow + part * 16 + 8);
#pragma unroll
        for (int u = 0; u < 8; ++u) {
            vds[part * 16 + u][key] = v0[u];
            vds[part * 16 + 8 + u][key] = v1[u];
        }
    }
    __syncthreads();
    const size_t cb = ((size_t)((b * HEADS + h) * 32) + blockIdx.x) * 4096;
#pragma unroll
    for (int p = 0; p < 2; ++p) {
        const int idx = p * 256 + t;
        const int frag = idx >> 6, lane = idx & 63;
        const int jn = frag >> 1, half = frag & 1, g = lane >> 4, c = lane & 15;
        *(f16x8*)(kfo + cb + frag * 512 + lane * 8) =
            *(const f16x8*)(&kds[jn * 16 + c][half * 32 + g * 8]);
    }
#pragma unroll
    for (int p = 0; p < 4; ++p) {
        const int idx = p * 256 + t;
        const int frag = idx >> 6, lane = idx & 63;
        const int jd = frag >> 2, jn = frag & 3, g = lane >> 4, c = lane & 15;
        *(f16x4*)(vfo + cb + frag * 256 + lane * 4) =
            *(const f16x4*)(&vds[jd * 16 + c][jn * 16 + 4 * g]);
    }
}

// ---------------------------------------------------------------------------
// MFMA flash attention, no split-K (r7/r9 structure) with T14 reg-staging
// (r10). attn line is CLOSED: r1/r3/r4/r5/r8/r10 all confirmed this loop as
// the local optimum (~54us).
// ---------------------------------------------------------------------------
__global__ __launch_bounds__(256, 2) void attn_f16(const f16* __restrict__ qkv,
                                                   const f16* __restrict__ kfr,
                                                   const f16* __restrict__ vfr,
                                                   f16* __restrict__ aof0) {
    __shared__ __align__(16) f16 kls[4096];     // one K chunk (8 KB)
    __shared__ __align__(16) f16 vls[4096];     // one V chunk (8 KB)
    __shared__ __align__(16) f16 ot[4][32][72]; // epilogue transpose (18 KB)
    const int tid = threadIdx.x;
    const int w = tid >> 6, lane = tid & 63;
    const int g = lane >> 4, c = lane & 15;

    // XCD-aware decode: wid -> (xcd, slot) -> (combo=(h,b), xblk)
    const int wid = blockIdx.x;                 // 0..511
    const int xcd = wid & 7, slot = wid >> 3;   // slot 0..63
    const int combo = xcd * 4 + (slot >> 4);    // 0..31: 4 (h,b) combos/XCD
    const int xblk = slot & 15;                 // 0..15
    const int h = combo & 15;
    const int b = combo >> 4;

    const int bh = b * HEADS + h;
    const int row0 = xblk * 128 + w * 32;

    const f16* qb = qkv + (size_t)(b * SEQ + row0) * 3072 + h * HEAD_DIM + g * 8;
    // per-thread staging addresses (wave w owns bytes [w*2KB, w*2KB+2KB))
    const f16* kfb = kfr + (size_t)bh * 32 * 4096 + w * 1024 + lane * 8;
    const f16* vfb = vfr + (size_t)bh * 32 * 4096 + w * 1024 + lane * 8;
    f16* kd = kls + w * 1024 + lane * 8;
    f16* vd = vls + w * 1024 + lane * 8;

    f16x8 qf[2][2];
#pragma unroll
    for (int i = 0; i < 2; ++i) {
        qf[i][0] = *(const f16x8*)(qb + (size_t)(i * 16 + c) * 3072);
        qf[i][1] = *(const f16x8*)(qb + (size_t)(i * 16 + c) * 3072 + 32);
    }
    const f32x4 z = {0.f, 0.f, 0.f, 0.f};
    f32x4 acc[4][2];
#pragma unroll
    for (int jd = 0; jd < 4; ++jd) { acc[jd][0] = z; acc[jd][1] = z; }
    float dloc[2] = {0.f, 0.f};   // denominator partials (VALU pipe)

    const float SC = 0.125f * 1.4426950408889634f;

    // prologue: chunk 0 -> regs
    f16x8 kr0 = *(const f16x8*)(kfb);
    f16x8 kr1 = *(const f16x8*)(kfb + 512);
    f16x8 vr0 = *(const f16x8*)(vfb);
    f16x8 vr1 = *(const f16x8*)(vfb + 512);

    for (int cc = 0; cc < 32; ++cc) {
        __syncthreads();   // prior chunk's ds_reads done; staging regs landed
        *(f16x8*)kd         = kr0;
        *(f16x8*)(kd + 512) = kr1;
        *(f16x8*)vd         = vr0;
        *(f16x8*)(vd + 512) = vr1;
        __syncthreads();   // ds_writes visible block-wide
        if (cc + 1 < 32) {
            // issue next chunk's loads AFTER the barrier: they stay in flight
            // across the whole compute phase (no exposed latency)
            const f16* kg = kfb + (size_t)(cc + 1) * 4096;
            const f16* vg = vfb + (size_t)(cc + 1) * 4096;
            kr0 = *(const f16x8*)(kg);
            kr1 = *(const f16x8*)(kg + 512);
            vr0 = *(const f16x8*)(vg);
            vr1 = *(const f16x8*)(vg + 512);
        }

        f16x8 kf[8];
        f16x4 vf[16];
#pragma unroll
        for (int f = 0; f < 8; ++f) kf[f] = *(const f16x8*)(kls + lane * 8 + f * 512);
#pragma unroll
        for (int f = 0; f < 16; ++f) vf[f] = *(const f16x4*)(vls + lane * 4 + f * 256);

#pragma unroll
        for (int i = 0; i < 2; ++i) {
            f32x4 s[4];
#pragma unroll
            for (int jn = 0; jn < 4; ++jn) {
                s[jn] = __builtin_amdgcn_mfma_f32_16x16x32_f16(kf[jn * 2], qf[i][0], z, 0, 0, 0);
                s[jn] = __builtin_amdgcn_mfma_f32_16x16x32_f16(kf[jn * 2 + 1], qf[i][1], s[jn], 0, 0, 0);
            }
#pragma unroll
            for (int jn = 0; jn < 4; ++jn) {
                const float e0 = __builtin_amdgcn_exp2f(fmaf(s[jn][0], SC, -8.0f));
                const float e1 = __builtin_amdgcn_exp2f(fmaf(s[jn][1], SC, -8.0f));
                const float e2 = __builtin_amdgcn_exp2f(fmaf(s[jn][2], SC, -8.0f));
                const float e3 = __builtin_amdgcn_exp2f(fmaf(s[jn][3], SC, -8.0f));
                dloc[i] += (e0 + e1) + (e2 + e3);
                f16x4 pf = {(f16)e0, (f16)e1, (f16)e2, (f16)e3};
#pragma unroll
                for (int jd = 0; jd < 4; ++jd)
                    acc[jd][i] = __builtin_amdgcn_mfma_f32_16x16x16f16(vf[jd * 4 + jn], pf, acc[jd][i], 0, 0, 0);
            }
        }
    }

    // denominators: reduce across the 4 g-groups (lanes c, 16+c, 32+c, 48+c);
    // after the two xors every lane holds the full sum for its query (i, c).
    float inv[2];
#pragma unroll
    for (int i = 0; i < 2; ++i) {
        dloc[i] += __shfl_xor(dloc[i], 16, 64);
        dloc[i] += __shfl_xor(dloc[i], 32, 64);
        inv[i] = 1.0f / dloc[i];   // 2^-8 bias cancels between num and denom
    }

    // numerator: normalize in f32, O^T regs -> wave-private LDS transpose ->
    // coalesced f16 store (single output, no combine pass)
    __syncthreads();   // all ds_reads of the last chunk done before ot reuse
#pragma unroll
    for (int i = 0; i < 2; ++i)
#pragma unroll
        for (int jd = 0; jd < 4; ++jd)
#pragma unroll
            for (int r = 0; r < 4; ++r)
                ot[w][i * 16 + c][jd * 16 + 4 * g + r] = (f16)(acc[jd][i][r] * inv[i]);
    const int tr = lane >> 1, hf = lane & 1;
    f16* aob = aof0 + (size_t)(b * SEQ + row0 + tr) * HIDDEN + h * HEAD_DIM + hf * 32;
#pragma unroll
    for (int q = 0; q < 4; ++q)
        *(f16x8*)(aob + q * 8) = *(const f16x8*)(&ot[w][tr][hf * 32 + q * 8]);
}

// ---------------------------------------------------------------------------
// launch
// ---------------------------------------------------------------------------
extern "C" void kernel_launch(void* const* d_in, const int* in_sizes, int n_in,
                              void* d_out, int out_size, void* d_ws, size_t ws_size,
                              hipStream_t stream) {
    const float* x   = (const float*)d_in[0];
    const float* W_q = (const float*)d_in[1];
    const float* W_k = (const float*)d_in[2];
    const float* W_v = (const float*)d_in[3];
    const float* W_o = (const float*)d_in[4];
    const float* rW1 = (const float*)d_in[5];
    const float* rb1 = (const float*)d_in[6];
    const float* rW2 = (const float*)d_in[7];
    const float* rb2 = (const float*)d_in[8];
    float* out = (float*)d_out;

    const size_t MAT = (size_t)TOKENS * HIDDEN;   // 4M
    const size_t WSZ = (size_t)HIDDEN * HIDDEN;   // 1M
    f16* x16  = (f16*)d_ws;
    f16* wqkv = x16 + MAT;            // [3072][1024]; wot contiguous after
    f16* wot  = wqkv + 3 * WSZ;
    f16* qkv  = wot + WSZ;            // [4096][3072]
    f16* kfr  = qkv + 3 * MAT;
    f16* vfr  = kfr + MAT;
    f16* aof0 = vfr + MAT;
    f16* aof1 = aof0 + MAT;           // unused (no split-K)
    f16* w1h  = aof1 + MAT;           // [128][1024]
    f16* w1l  = w1h + POS_DIM * HIDDEN;
    float* raw    = (float*)(w1l + POS_DIM * HIDDEN);
    float* pos    = raw + TOKENS;
    float* costab = pos + TOKENS;
    float* sintab = costab + TOKENS * 32;

    // merged preprocessing: cast_x (2048) + cast_wt4 (4096) + cast_w1t (128)
    cast_all_kernel<<<6272, 256, 0, stream>>>(x, W_q, W_k, W_v, W_o, rW1,
                                              x16, wqkv, w1h, w1l);

    // fused qkv GEMM (BM=64: 1536 blocks) + repo MLP (64 blocks, dispatched
    // first): repo's serial slot gone (r12), gemm now ~5-6 blocks/CU
    gemm_repo_kernel<<<1600, 256, 0, stream>>>(x16, wqkv, qkv,
                                               x, w1h, w1l, rb1, rW2, rb2, raw);

    repo_cumsum_kernel<<<BATCH, 256, 0, stream>>>(raw, pos);
    sctab_kernel<<<TOKENS * 32 / 256, 256, 0, stream>>>(pos, costab, sintab);

    packkv_kernel<<<dim3(SEQ / 64, HEADS, BATCH), 256, 0, stream>>>(qkv, costab, sintab, kfr, vfr);

    attn_f16<<<dim3(512), 256, 0, stream>>>(qkv, kfr, vfr, aof0);

    // out projection: 64x64 tiles -> grid (16,64) = 1024 blocks = 4/CU
    gemm_gll64<<<dim3(16, 64), 256, 0, stream>>>(aof0, wot, out, 1024);
}